// Round 1
// baseline (2550.450 us; speedup 1.0000x reference)
//
#include <hip/hip_runtime.h>
#include <math.h>

#define CDIV(a,b) (((a)+(b)-1)/(b))

__device__ __forceinline__ float warp_sum(float v){
  #pragma unroll
  for (int o=32;o;o>>=1) v += __shfl_down(v,o);
  return v;
}

// ---------- small vector kernels ----------
__global__ __launch_bounds__(256)
void k_rowdot(const float* __restrict__ A, const float* __restrict__ alt,
              const float* __restrict__ q, float* __restrict__ out,
              int rows, int textRows){
  int wid = threadIdx.x>>6, lane = threadIdx.x&63;
  int row = blockIdx.x*4 + wid;
  if (row >= rows) return;
  const float* src = (row < textRows) ? (A + (size_t)row*256) : alt;
  float4 a = *(const float4*)(src + lane*4);
  float4 b = *(const float4*)(q + lane*4);
  float s = a.x*b.x + a.y*b.y + a.z*b.z + a.w*b.w;
  s = warp_sum(s);
  if (!lane) out[row] = s;
}

__global__ void k_tri(const int* __restrict__ h, const int* __restrict__ r,
                      const int* __restrict__ t, const float* __restrict__ qe,
                      const float* __restrict__ qr, float* __restrict__ tri, int E){
  int e = blockIdx.x*256 + threadIdx.x; if (e>=E) return;
  tri[e] = qe[h[e]] + qr[r[e]] + qe[t[e]];
}

// ---------- top-32 (exact, with jax tie-break: lower index first) ----------
__global__ void k_bmax(const float* __restrict__ tri, float* __restrict__ bmax, int E){
  __shared__ float red[256];
  int chunk = CDIV(E, (int)gridDim.x);
  int lo = blockIdx.x*chunk, hi = min(E, lo+chunk);
  float m = -INFINITY;
  for (int i=lo+threadIdx.x; i<hi; i+=256) m = fmaxf(m, tri[i]);
  red[threadIdx.x]=m; __syncthreads();
  for (int s=128;s;s>>=1){ if ((int)threadIdx.x<s) red[threadIdx.x]=fmaxf(red[threadIdx.x],red[threadIdx.x+s]); __syncthreads(); }
  if (!threadIdx.x) bmax[blockIdx.x]=red[0];
}

__global__ void k_thresh(const float* __restrict__ bmax, float* __restrict__ thrT){
  __shared__ float v[256];
  __shared__ float red[256];
  __shared__ int who;
  int t = threadIdx.x;
  v[t] = bmax[t];
  __syncthreads();
  for (int it=0; it<32; it++){
    red[t]=v[t]; __syncthreads();
    for (int s=128;s;s>>=1){ if (t<s) red[t]=fmaxf(red[t],red[t+s]); __syncthreads(); }
    float m = red[0];
    if (it==31 && t==0) thrT[0]=m;
    if (t==0) who = 256;
    __syncthreads();
    if (v[t]==m) atomicMin(&who, t);
    __syncthreads();
    if (t==who) v[t] = -INFINITY;
    __syncthreads();
  }
}

__global__ void k_compact(const float* __restrict__ tri, const float* __restrict__ thrT,
                          int* __restrict__ cnt, int* __restrict__ ci, float* __restrict__ cv, int E){
  int e = blockIdx.x*256 + threadIdx.x; if (e>=E) return;
  float v = tri[e];
  if (v >= thrT[0]){
    int p = atomicAdd(cnt, 1);
    ci[p]=e; cv[p]=v;
  }
}

__global__ __launch_bounds__(256)
void k_final32(const int* __restrict__ ci, float* __restrict__ cv, const int* __restrict__ cnt,
               int* __restrict__ ai, float* __restrict__ as){
  int C = *cnt;
  int t = threadIdx.x;
  __shared__ float rv[256]; __shared__ int ri[256]; __shared__ int rp[256];
  for (int it=0; it<32; it++){
    float bv=-INFINITY; int bi=0x7fffffff; int bp=-1;
    for (int p=t; p<C; p+=256){
      float v = cv[p]; int i = ci[p];
      if (v>bv || (v==bv && i<bi)){ bv=v; bi=i; bp=p; }
    }
    rv[t]=bv; ri[t]=bi; rp[t]=bp; __syncthreads();
    for (int s=128;s;s>>=1){
      if (t<s){
        if (rv[t+s]>rv[t] || (rv[t+s]==rv[t] && ri[t+s]<ri[t])){ rv[t]=rv[t+s]; ri[t]=ri[t+s]; rp[t]=rp[t+s]; }
      }
      __syncthreads();
    }
    if (t==0){ ai[it]=ri[0]; as[it]=rv[0]; cv[rp[0]] = -INFINITY; }
    __syncthreads();
  }
}

// ---------- graph PE kernels ----------
__global__ void k_topic(const int* __restrict__ ids, float* __restrict__ topic, int n){
  if ((int)threadIdx.x < n) topic[ids[threadIdx.x]] = 1.f;
}
__global__ void k_amask(const int* __restrict__ ai, const int* __restrict__ h,
                        const int* __restrict__ t, float* __restrict__ amask){
  int k = threadIdx.x; if (k>=32) return;
  int e = ai[k];
  amask[h[e]] = 1.f;
  amask[t[e]] = 1.f;
}
__global__ void k_deg(const int* __restrict__ h, const int* __restrict__ t,
                      float* __restrict__ degt, float* __restrict__ degh, int E){
  int e = blockIdx.x*256+threadIdx.x; if (e>=E) return;
  atomicAdd(&degt[t[e]], 1.f);
  atomicAdd(&degh[h[e]], 1.f);
}
__global__ void k_copyf(const float* __restrict__ a, float* __restrict__ b, int n){
  int i = blockIdx.x*256+threadIdx.x; if (i<n) b[i]=a[i];
}
__global__ void k_dde_edge(const int* __restrict__ src, const int* __restrict__ dst,
                           const float* __restrict__ s, float* __restrict__ sn, int E){
  int e = blockIdx.x*256+threadIdx.x; if (e>=E) return;
  atomicAdd(&sn[dst[e]], s[src[e]]);
}
__global__ void k_dde_div(float* __restrict__ sn, const float* __restrict__ deg,
                          float* __restrict__ pe4, int col, int N){
  int i = blockIdx.x*256+threadIdx.x; if (i>=N) return;
  float v = sn[i] / fmaxf(deg[i], 1.f);
  sn[i] = v;
  pe4[i*4+col] = v;
}
__global__ void k_dist_init(const float* __restrict__ amask, int* __restrict__ dist, int N){
  int i = blockIdx.x*256+threadIdx.x; if (i>=N) return;
  dist[i] = (amask[i] > 0.f) ? 0 : 4;
}
__global__ void k_fill2(int* __restrict__ c1, int* __restrict__ c2, int val, int N){
  int i = blockIdx.x*256+threadIdx.x; if (i>=N) return;
  c1[i]=val; c2[i]=val;
}
__global__ void k_bfs_edge(const int* __restrict__ h, const int* __restrict__ t,
                           const int* __restrict__ dist, int* __restrict__ c1, int* __restrict__ c2, int E){
  int e = blockIdx.x*256+threadIdx.x; if (e>=E) return;
  int hh=h[e], tt=t[e];
  atomicMin(&c1[tt], dist[hh]+1);
  atomicMin(&c2[hh], dist[tt]+1);
}
__global__ void k_bfs_comb(int* __restrict__ dist, const int* __restrict__ c1, const int* __restrict__ c2, int N){
  int i = blockIdx.x*256+threadIdx.x; if (i>=N) return;
  dist[i] = min(dist[i], min(c1[i], c2[i]));
}

// ---------- tiny dense helpers ----------
__global__ void k_distW(const float* __restrict__ dist_emb, const float* __restrict__ W_enc,
                        float* __restrict__ distW){
  int d = blockIdx.x, j = threadIdx.x;
  const float* Wpe = W_enc + (256+4)*256;   // rows 260..275
  float s=0.f;
  #pragma unroll
  for (int p=0;p<16;p++) s += dist_emb[d*16+p]*Wpe[p*256+j];
  distW[d*256+j]=s;
}
__global__ void k_colvec(const float* __restrict__ x, const float* __restrict__ W,
                         const float* __restrict__ bias, float* __restrict__ out){
  int j = threadIdx.x; float s = bias ? bias[j] : 0.f;
  for (int k=0;k<256;k++) s += x[k]*W[k*256+j];
  out[j]=s;
}

__global__ __launch_bounds__(256)
void k_enc_fin(const float* __restrict__ enc_text, const float* __restrict__ enc_nt,
               const float* __restrict__ b_enc, const float* __restrict__ W_enc,
               const float* __restrict__ pe4, const int* __restrict__ dist,
               const float* __restrict__ topic, const float* __restrict__ amask,
               const float* __restrict__ distW, float* __restrict__ h, int N, int Ntext){
  int i = blockIdx.x, j = threadIdx.x;
  if (i>=N) return;
  const float* Wpe = W_enc + 256*256;
  float base = (i < Ntext) ? enc_text[(size_t)i*256+j] : enc_nt[j];
  float p0=pe4[i*4+0], p1=pe4[i*4+1], p2=pe4[i*4+2], p3=pe4[i*4+3];
  int d = dist[i];
  float tp = topic[i], am = amask[i];
  float v = base + b_enc[j] + Wpe[22*256+j]
          + p0*Wpe[0*256+j] + p1*Wpe[1*256+j] + p2*Wpe[2*256+j] + p3*Wpe[3*256+j]
          + distW[d*256+j]
          + tp*Wpe[20*256+j] + am*Wpe[21*256+j];
  h[(size_t)i*256+j] = fmaxf(v, 0.f);
}

// ---------- generic fp32 tiled GEMM (A may be a concat of A1|A2 along K) ----------
__global__ __launch_bounds__(256)
void k_gemm(const float* __restrict__ A1, int lda1,
            const float* __restrict__ A2, int lda2, int K1,
            const float* __restrict__ B, int ldb,
            float* __restrict__ C, int ldc,
            int M, int N, int K)
{
  __shared__ __align__(16) float As[16][132];
  __shared__ __align__(16) float Bs[16][132];
  const int tid = threadIdx.x;
  const int bm = blockIdx.y * 128, bn = blockIdx.x * 128;
  const int tx = tid & 15, ty = tid >> 4;
  float acc[8][8];
  #pragma unroll
  for (int i=0;i<8;i++)
    #pragma unroll
    for (int j=0;j<8;j++) acc[i][j]=0.f;

  for (int k0=0;k0<K;k0+=16){
    #pragma unroll
    for (int i=0;i<2;i++){
      int f = tid + i*256;
      int r = f >> 2;
      int c = (f & 3) << 2;
      int row = bm + r;
      float4 v = make_float4(0.f,0.f,0.f,0.f);
      if (row < M){
        int kc = k0 + c;
        const float* src = (kc < K1) ? (A1 + (size_t)row*lda1 + kc)
                                     : (A2 + (size_t)row*lda2 + (kc - K1));
        v = *(const float4*)src;
      }
      As[c+0][r]=v.x; As[c+1][r]=v.y; As[c+2][r]=v.z; As[c+3][r]=v.w;
    }
    #pragma unroll
    for (int i=0;i<2;i++){
      int f = tid + i*256;
      int r = f >> 5;
      int c = (f & 31) << 2;
      int col = bn + c;
      float4 v = make_float4(0.f,0.f,0.f,0.f);
      if (col < N) v = *(const float4*)(B + (size_t)(k0+r)*ldb + col);
      *(float4*)&Bs[r][c] = v;
    }
    __syncthreads();
    #pragma unroll
    for (int kk=0;kk<16;kk++){
      float a[8], b[8];
      *(float4*)&a[0] = *(const float4*)&As[kk][ty*8];
      *(float4*)&a[4] = *(const float4*)&As[kk][ty*8+4];
      *(float4*)&b[0] = *(const float4*)&Bs[kk][tx*8];
      *(float4*)&b[4] = *(const float4*)&Bs[kk][tx*8+4];
      #pragma unroll
      for (int i=0;i<8;i++)
        #pragma unroll
        for (int j=0;j<8;j++)
          acc[i][j] = fmaf(a[i], b[j], acc[i][j]);
    }
    __syncthreads();
  }
  #pragma unroll
  for (int i=0;i<8;i++){
    int row = bm + ty*8 + i;
    if (row < M){
      int col = bn + tx*8;
      if (col < N){
        *(float4*)(C + (size_t)row*ldc + col)     = *(float4*)&acc[i][0];
        *(float4*)(C + (size_t)row*ldc + col + 4) = *(float4*)&acc[i][4];
      }
    }
  }
}

// ---------- GNN edge kernels ----------
__global__ __launch_bounds__(256)
void k_msg(const int* __restrict__ h_ids, const int* __restrict__ r_ids, const int* __restrict__ t_ids,
           const float* __restrict__ hm, const float* __restrict__ mrel, float* __restrict__ agg, int E){
  int wid = threadIdx.x>>6, lane = threadIdx.x&63;
  int e = blockIdx.x*4 + wid; if (e>=E) return;
  int h=h_ids[e], r=r_ids[e], t=t_ids[e];
  int c = lane*4;
  float4 a = *(const float4*)(hm + (size_t)h*256 + c);
  float4 b = *(const float4*)(mrel + (size_t)r*256 + c);
  float4 v;
  v.x=fmaxf(a.x+b.x,0.f); v.y=fmaxf(a.y+b.y,0.f); v.z=fmaxf(a.z+b.z,0.f); v.w=fmaxf(a.w+b.w,0.f);
  float* dst = agg + (size_t)t*256 + c;
  atomicAdd(dst+0, v.x); atomicAdd(dst+1, v.y); atomicAdd(dst+2, v.z); atomicAdd(dst+3, v.w);
}

__global__ void k_update(const float* __restrict__ hin, const float* __restrict__ gpre,
                         float* __restrict__ hout /* holds upd_pre in-place */, int total){
  int i = blockIdx.x*256+threadIdx.x; if (i>=total) return;
  float g = 1.f/(1.f+expf(-gpre[i]));
  hout[i] = hin[i] + g * tanhf(hout[i]);
}

// ---------- scorer ----------
__global__ __launch_bounds__(256)
void k_score(const int* __restrict__ h_ids, const int* __restrict__ r_ids, const int* __restrict__ t_ids,
             const float* __restrict__ uh, const float* __restrict__ ut, const float* __restrict__ vr,
             const float* __restrict__ bias2, const float* __restrict__ topic,
             const int* __restrict__ aidx, const float* __restrict__ asc,
             const float* __restrict__ W1s /* rows 1024..1027 */, const float* __restrict__ W2,
             const float* __restrict__ b2, float* __restrict__ out, int E){
  __shared__ int s_ai[32]; __shared__ float s_as[32];
  if (threadIdx.x < 32){ s_ai[threadIdx.x]=aidx[threadIdx.x]; s_as[threadIdx.x]=asc[threadIdx.x]; }
  __syncthreads();
  int wid = threadIdx.x>>6, lane = threadIdx.x&63;
  int e = blockIdx.x*4 + wid; if (e>=E) return;
  int h=h_ids[e], r=r_ids[e], t=t_ids[e];
  float isA=0.f, aS=0.f;
  #pragma unroll
  for (int k=0;k<32;k++){ if (s_ai[k]==e){ isA=1.f; aS=s_as[k]; } }
  float th=topic[h], tt=topic[t];
  int c = lane*4;
  float4 acc = *(const float4*)(bias2 + c);
  float4 a = *(const float4*)(uh + (size_t)h*256 + c);
  float4 b = *(const float4*)(vr + (size_t)r*256 + c);
  float4 d = *(const float4*)(ut + (size_t)t*256 + c);
  acc.x += a.x+b.x+d.x; acc.y += a.y+b.y+d.y; acc.z += a.z+b.z+d.z; acc.w += a.w+b.w+d.w;
  float4 w0 = *(const float4*)(W1s + 0*256 + c);
  float4 w1 = *(const float4*)(W1s + 1*256 + c);
  float4 w2 = *(const float4*)(W1s + 2*256 + c);
  float4 w3 = *(const float4*)(W1s + 3*256 + c);
  acc.x += isA*w0.x + aS*w1.x + th*w2.x + tt*w3.x;
  acc.y += isA*w0.y + aS*w1.y + th*w2.y + tt*w3.y;
  acc.z += isA*w0.z + aS*w1.z + th*w2.z + tt*w3.z;
  acc.w += isA*w0.w + aS*w1.w + th*w2.w + tt*w3.w;
  acc.x=fmaxf(acc.x,0.f); acc.y=fmaxf(acc.y,0.f); acc.z=fmaxf(acc.z,0.f); acc.w=fmaxf(acc.w,0.f);
  float4 w = *(const float4*)(W2 + c);
  float p = acc.x*w.x + acc.y*w.y + acc.z*w.z + acc.w*w.w;
  p = warp_sum(p);
  if (!lane) out[e] = p + b2[0];
}

// ---------- host ----------
extern "C" void kernel_launch(void* const* d_in, const int* in_sizes, int n_in,
                              void* d_out, int out_size, void* d_ws, size_t ws_size,
                              hipStream_t stream)
{
  const int*   h_ids   = (const int*)d_in[0];
  const int*   r_ids   = (const int*)d_in[1];
  const int*   t_ids   = (const int*)d_in[2];
  const float* q       = (const float*)d_in[3];
  const float* ent     = (const float*)d_in[4];
  const float* rel     = (const float*)d_in[5];
  const int*   topicId = (const int*)d_in[6];
  const float* nontext = (const float*)d_in[9];
  const float* dist_e  = (const float*)d_in[10];
  const float* W_enc   = (const float*)d_in[11];
  const float* b_enc   = (const float*)d_in[12];
  const float* W_msg   = (const float*)d_in[13];
  const float* W_gate  = (const float*)d_in[14];
  const float* W_upd   = (const float*)d_in[15];
  const float* W_out   = (const float*)d_in[16];
  const float* W1      = (const float*)d_in[17];
  const float* b1      = (const float*)d_in[18];
  const float* W2      = (const float*)d_in[19];
  const float* b2      = (const float*)d_in[20];
  float* out = (float*)d_out;

  const int E = in_sizes[0];
  const int Ntext = in_sizes[4]/256;
  const int R = in_sizes[5]/256;
  const int NT = 500;                 // num_non_text_entities (fixed by problem)
  const int N = Ntext + NT;
  const int nTopic = in_sizes[6];

  char* ws = (char*)d_ws;
  size_t off = 0;
  auto alloc = [&](size_t bytes)->void*{
    size_t o = (off + 255) & ~(size_t)255;
    off = o + bytes;
    return (void*)(ws + o);
  };
  float* B1    = (float*)alloc((size_t)N*256*4);
  float* B2    = (float*)alloc((size_t)N*256*4);
  float* B3    = (float*)alloc((size_t)N*256*4);   // agg / u_h
  float* B4    = (float*)alloc((size_t)N*256*4);   // hm / gate_pre / u_t
  float* qe    = (float*)alloc((size_t)N*4);
  float* qr    = (float*)alloc((size_t)R*4);
  float* tri   = (float*)alloc((size_t)E*4);
  float* bmax  = (float*)alloc(256*4);
  float* thrT  = (float*)alloc(4);
  int*   cnt   = (int*)  alloc(4);
  int*   ci    = (int*)  alloc((size_t)E*4);
  float* cv    = (float*)alloc((size_t)E*4);
  int*   ai    = (int*)  alloc(32*4);
  float* as    = (float*)alloc(32*4);
  float* topic = (float*)alloc((size_t)N*4);
  float* amask = (float*)alloc((size_t)N*4);
  float* degt  = (float*)alloc((size_t)N*4);
  float* degh  = (float*)alloc((size_t)N*4);
  float* sA    = (float*)alloc((size_t)N*4);
  float* sB    = (float*)alloc((size_t)N*4);
  float* pe4   = (float*)alloc((size_t)N*16);
  int*   dist  = (int*)  alloc((size_t)N*4);
  int*   c1    = (int*)  alloc((size_t)N*4);
  int*   c2    = (int*)  alloc((size_t)N*4);
  float* distW = (float*)alloc(5*256*4);
  float* encnt = (float*)alloc(256*4);
  float* mrel  = (float*)alloc((size_t)R*256*4);
  float* vrel  = (float*)alloc((size_t)R*256*4);
  float* bias2 = (float*)alloc(256*4);
  (void)ws_size; (void)n_in; (void)out_size;

  // ---- zero init ----
  hipMemsetAsync(cnt,   0, 4, stream);
  hipMemsetAsync(topic, 0, (size_t)N*4, stream);
  hipMemsetAsync(amask, 0, (size_t)N*4, stream);
  hipMemsetAsync(degt,  0, (size_t)N*4, stream);
  hipMemsetAsync(degh,  0, (size_t)N*4, stream);

  // ---- triple scores + top-32 ----
  k_rowdot<<<CDIV(N,4),256,0,stream>>>(ent, nontext, q, qe, N, Ntext);
  k_rowdot<<<CDIV(R,4),256,0,stream>>>(rel, nontext, q, qr, R, R);
  k_tri<<<CDIV(E,256),256,0,stream>>>(h_ids, r_ids, t_ids, qe, qr, tri, E);
  k_bmax<<<256,256,0,stream>>>(tri, bmax, E);
  k_thresh<<<1,256,0,stream>>>(bmax, thrT);
  k_compact<<<CDIV(E,256),256,0,stream>>>(tri, thrT, cnt, ci, cv, E);
  k_final32<<<1,256,0,stream>>>(ci, cv, cnt, ai, as);

  // ---- topic / anchor masks / degrees ----
  k_topic<<<1,64,0,stream>>>(topicId, topic, nTopic);
  k_amask<<<1,32,0,stream>>>(ai, h_ids, t_ids, amask);
  k_deg<<<CDIV(E,256),256,0,stream>>>(h_ids, t_ids, degt, degh, E);

  // ---- DDE label propagation (2 fwd + 2 rev) ----
  {
    float* cur=sA; float* nxt=sB;
    k_copyf<<<CDIV(N,256),256,0,stream>>>(topic, cur, N);
    for (int r0=0;r0<2;r0++){
      hipMemsetAsync(nxt, 0, (size_t)N*4, stream);
      k_dde_edge<<<CDIV(E,256),256,0,stream>>>(h_ids, t_ids, cur, nxt, E);
      k_dde_div<<<CDIV(N,256),256,0,stream>>>(nxt, degt, pe4, r0, N);
      float* tmp=cur; cur=nxt; nxt=tmp;
    }
    k_copyf<<<CDIV(N,256),256,0,stream>>>(topic, cur, N);
    for (int r0=0;r0<2;r0++){
      hipMemsetAsync(nxt, 0, (size_t)N*4, stream);
      k_dde_edge<<<CDIV(E,256),256,0,stream>>>(t_ids, h_ids, cur, nxt, E);
      k_dde_div<<<CDIV(N,256),256,0,stream>>>(nxt, degh, pe4, 2+r0, N);
      float* tmp=cur; cur=nxt; nxt=tmp;
    }
  }

  // ---- bounded BFS from anchor endpoints ----
  k_dist_init<<<CDIV(N,256),256,0,stream>>>(amask, dist, N);
  for (int it=0; it<3; it++){
    k_fill2<<<CDIV(N,256),256,0,stream>>>(c1, c2, 4, N);
    k_bfs_edge<<<CDIV(E,256),256,0,stream>>>(h_ids, t_ids, dist, c1, c2, E);
    k_bfs_comb<<<CDIV(N,256),256,0,stream>>>(dist, c1, c2, N);
  }

  // ---- encoder ----
  k_distW<<<5,256,0,stream>>>(dist_e, W_enc, distW);
  k_colvec<<<1,256,0,stream>>>(nontext, W_enc, nullptr, encnt);
  k_gemm<<<dim3(2,CDIV(Ntext,128)),256,0,stream>>>(ent,256, ent,256, 256, W_enc,256, B2,256, Ntext,256,256);
  k_enc_fin<<<N,256,0,stream>>>(B2, encnt, b_enc, W_enc, pe4, dist, topic, amask, distW, B1, N, Ntext);

  // ---- 2-layer gated GNN ----
  for (int l=0;l<2;l++){
    const float* Wm = W_msg  + (size_t)l*512*256;
    const float* Wg = W_gate + (size_t)l*512*256;
    const float* Wu = W_upd  + (size_t)l*256*256;
    float* hin  = l ? B2 : B1;
    float* hout = l ? B1 : B2;
    // mrel = rel @ Wm[256:512]
    k_gemm<<<dim3(2,CDIV(R,128)),256,0,stream>>>(rel,256, rel,256, 256, Wm+256*256,256, mrel,256, R,256,256);
    // hm = h @ Wm[0:256]  -> B4
    k_gemm<<<dim3(2,CDIV(N,128)),256,0,stream>>>(hin,256, hin,256, 256, Wm,256, B4,256, N,256,256);
    // agg = scatter_add relu(hm[h]+mrel[r]) at t  -> B3
    hipMemsetAsync(B3, 0, (size_t)N*256*4, stream);
    k_msg<<<CDIV(E,4),256,0,stream>>>(h_ids, r_ids, t_ids, B4, mrel, B3, E);
    // gate_pre = [h,agg] @ Wg -> B4 ; upd_pre = agg @ Wu -> hout
    k_gemm<<<dim3(2,CDIV(N,128)),256,0,stream>>>(hin,256, B3,256, 256, Wg,256, B4,256, N,256,512);
    k_gemm<<<dim3(2,CDIV(N,128)),256,0,stream>>>(B3,256, B3,256, 256, Wu,256, hout,256, N,256,256);
    // hout = hin + sigmoid(gate_pre)*tanh(upd_pre)
    k_update<<<CDIV(N*256,256),256,0,stream>>>(hin, B4, hout, N*256);
  }

  // ---- output head: h_final = h @ W_out (h is in B1) ----
  k_gemm<<<dim3(2,CDIV(N,128)),256,0,stream>>>(B1,256, B1,256, 256, W_out,256, B2,256, N,256,256);
  // u_h = hf @ W1[256:512] -> B3 ; u_t = hf @ W1[768:1024] -> B4 ; vrel = rel @ W1[512:768]
  k_gemm<<<dim3(2,CDIV(N,128)),256,0,stream>>>(B2,256, B2,256, 256, W1+(size_t)256*256,256, B3,256, N,256,256);
  k_gemm<<<dim3(2,CDIV(N,128)),256,0,stream>>>(B2,256, B2,256, 256, W1+(size_t)768*256,256, B4,256, N,256,256);
  k_gemm<<<dim3(2,CDIV(R,128)),256,0,stream>>>(rel,256, rel,256, 256, W1+(size_t)512*256,256, vrel,256, R,256,256);
  // bias2 = b1 + q @ W1[0:256]
  k_colvec<<<1,256,0,stream>>>(q, W1, b1, bias2);

  // ---- final scorer over all edges ----
  k_score<<<CDIV(E,4),256,0,stream>>>(h_ids, r_ids, t_ids, B3, B4, vrel, bias2, topic,
                                      ai, as, W1+(size_t)1024*256, W2, b2, out, E);
}

// Round 2
// 1324.627 us; speedup vs baseline: 1.9254x; 1.9254x over previous
//
#include <hip/hip_runtime.h>
#include <math.h>

#define CDIV(a,b) (((a)+(b)-1)/(b))

__device__ __forceinline__ float warp_sum(float v){
  #pragma unroll
  for (int o=32;o;o>>=1) v += __shfl_down(v,o);
  return v;
}

// ---------- small vector kernels ----------
__global__ __launch_bounds__(256)
void k_rowdot(const float* __restrict__ A, const float* __restrict__ alt,
              const float* __restrict__ q, float* __restrict__ out,
              int rows, int textRows){
  int wid = threadIdx.x>>6, lane = threadIdx.x&63;
  int row = blockIdx.x*4 + wid;
  if (row >= rows) return;
  const float* src = (row < textRows) ? (A + (size_t)row*256) : alt;
  float4 a = *(const float4*)(src + lane*4);
  float4 b = *(const float4*)(q + lane*4);
  float s = a.x*b.x + a.y*b.y + a.z*b.z + a.w*b.w;
  s = warp_sum(s);
  if (!lane) out[row] = s;
}

__global__ void k_tri(const int* __restrict__ h, const int* __restrict__ r,
                      const int* __restrict__ t, const float* __restrict__ qe,
                      const float* __restrict__ qr, float* __restrict__ tri, int E){
  int e = blockIdx.x*256 + threadIdx.x; if (e>=E) return;
  tri[e] = qe[h[e]] + qr[r[e]] + qe[t[e]];
}

// ---------- top-32 (exact, with jax tie-break: lower index first) ----------
__global__ void k_bmax(const float* __restrict__ tri, float* __restrict__ bmax, int E){
  __shared__ float red[256];
  int chunk = CDIV(E, (int)gridDim.x);
  int lo = blockIdx.x*chunk, hi = min(E, lo+chunk);
  float m = -INFINITY;
  for (int i=lo+threadIdx.x; i<hi; i+=256) m = fmaxf(m, tri[i]);
  red[threadIdx.x]=m; __syncthreads();
  for (int s=128;s;s>>=1){ if ((int)threadIdx.x<s) red[threadIdx.x]=fmaxf(red[threadIdx.x],red[threadIdx.x+s]); __syncthreads(); }
  if (!threadIdx.x) bmax[blockIdx.x]=red[0];
}

__global__ void k_thresh(const float* __restrict__ bmax, float* __restrict__ thrT){
  __shared__ float v[256];
  __shared__ float red[256];
  __shared__ int who;
  int t = threadIdx.x;
  v[t] = bmax[t];
  __syncthreads();
  for (int it=0; it<32; it++){
    red[t]=v[t]; __syncthreads();
    for (int s=128;s;s>>=1){ if (t<s) red[t]=fmaxf(red[t],red[t+s]); __syncthreads(); }
    float m = red[0];
    if (it==31 && t==0) thrT[0]=m;
    if (t==0) who = 256;
    __syncthreads();
    if (v[t]==m) atomicMin(&who, t);
    __syncthreads();
    if (t==who) v[t] = -INFINITY;
    __syncthreads();
  }
}

__global__ void k_compact(const float* __restrict__ tri, const float* __restrict__ thrT,
                          int* __restrict__ cnt, int* __restrict__ ci, float* __restrict__ cv, int E){
  int e = blockIdx.x*256 + threadIdx.x; if (e>=E) return;
  float v = tri[e];
  if (v >= thrT[0]){
    int p = atomicAdd(cnt, 1);
    ci[p]=e; cv[p]=v;
  }
}

__global__ __launch_bounds__(256)
void k_final32(const int* __restrict__ ci, float* __restrict__ cv, const int* __restrict__ cnt,
               int* __restrict__ ai, float* __restrict__ as){
  int C = *cnt;
  int t = threadIdx.x;
  __shared__ float rv[256]; __shared__ int ri[256]; __shared__ int rp[256];
  for (int it=0; it<32; it++){
    float bv=-INFINITY; int bi=0x7fffffff; int bp=-1;
    for (int p=t; p<C; p+=256){
      float v = cv[p]; int i = ci[p];
      if (v>bv || (v==bv && i<bi)){ bv=v; bi=i; bp=p; }
    }
    rv[t]=bv; ri[t]=bi; rp[t]=bp; __syncthreads();
    for (int s=128;s;s>>=1){
      if (t<s){
        if (rv[t+s]>rv[t] || (rv[t+s]==rv[t] && ri[t+s]<ri[t])){ rv[t]=rv[t+s]; ri[t]=ri[t+s]; rp[t]=rp[t+s]; }
      }
      __syncthreads();
    }
    if (t==0){ ai[it]=ri[0]; as[it]=rv[0]; cv[rp[0]] = -INFINITY; }
    __syncthreads();
  }
}

// ---------- graph PE kernels ----------
__global__ void k_topic(const int* __restrict__ ids, float* __restrict__ topic, int n){
  if ((int)threadIdx.x < n) topic[ids[threadIdx.x]] = 1.f;
}
__global__ void k_amask(const int* __restrict__ ai, const int* __restrict__ h,
                        const int* __restrict__ t, float* __restrict__ amask){
  int k = threadIdx.x; if (k>=32) return;
  int e = ai[k];
  amask[h[e]] = 1.f;
  amask[t[e]] = 1.f;
}
__global__ void k_deg(const int* __restrict__ h, const int* __restrict__ t,
                      float* __restrict__ degt, float* __restrict__ degh, int E){
  int e = blockIdx.x*256+threadIdx.x; if (e>=E) return;
  atomicAdd(&degt[t[e]], 1.f);
  atomicAdd(&degh[h[e]], 1.f);
}
__global__ void k_copyf(const float* __restrict__ a, float* __restrict__ b, int n){
  int i = blockIdx.x*256+threadIdx.x; if (i<n) b[i]=a[i];
}
__global__ void k_dde_edge(const int* __restrict__ src, const int* __restrict__ dst,
                           const float* __restrict__ s, float* __restrict__ sn, int E){
  int e = blockIdx.x*256+threadIdx.x; if (e>=E) return;
  atomicAdd(&sn[dst[e]], s[src[e]]);
}
__global__ void k_dde_div(float* __restrict__ sn, const float* __restrict__ deg,
                          float* __restrict__ pe4, int col, int N){
  int i = blockIdx.x*256+threadIdx.x; if (i>=N) return;
  float v = sn[i] / fmaxf(deg[i], 1.f);
  sn[i] = v;
  pe4[i*4+col] = v;
}
__global__ void k_dist_init(const float* __restrict__ amask, int* __restrict__ dist, int N){
  int i = blockIdx.x*256+threadIdx.x; if (i>=N) return;
  dist[i] = (amask[i] > 0.f) ? 0 : 4;
}
__global__ void k_fill2(int* __restrict__ c1, int* __restrict__ c2, int val, int N){
  int i = blockIdx.x*256+threadIdx.x; if (i>=N) return;
  c1[i]=val; c2[i]=val;
}
__global__ void k_bfs_edge(const int* __restrict__ h, const int* __restrict__ t,
                           const int* __restrict__ dist, int* __restrict__ c1, int* __restrict__ c2, int E){
  int e = blockIdx.x*256+threadIdx.x; if (e>=E) return;
  int hh=h[e], tt=t[e];
  atomicMin(&c1[tt], dist[hh]+1);
  atomicMin(&c2[hh], dist[tt]+1);
}
__global__ void k_bfs_comb(int* __restrict__ dist, const int* __restrict__ c1, const int* __restrict__ c2, int N){
  int i = blockIdx.x*256+threadIdx.x; if (i>=N) return;
  dist[i] = min(dist[i], min(c1[i], c2[i]));
}

// ---------- CSR build (bucket edges by destination t) ----------
__global__ void k_hist(const int* __restrict__ t, int* __restrict__ degi, int E){
  int e = blockIdx.x*256+threadIdx.x; if (e>=E) return;
  atomicAdd(&degi[t[e]], 1);
}
__global__ void k_scan1(const int* __restrict__ deg, int* __restrict__ offs,
                        int* __restrict__ bsum, int N){
  __shared__ int s[256];
  int i = blockIdx.x*256 + threadIdx.x;
  int v = (i<N) ? deg[i] : 0;
  s[threadIdx.x] = v; __syncthreads();
  #pragma unroll
  for (int o=1;o<256;o<<=1){
    int add = (threadIdx.x>=(unsigned)o) ? s[threadIdx.x-o] : 0; __syncthreads();
    s[threadIdx.x] += add; __syncthreads();
  }
  if (i<N) offs[i] = s[threadIdx.x] - v;   // exclusive
  if (threadIdx.x==255) bsum[blockIdx.x] = s[255];
}
__global__ void k_scan2(int* __restrict__ bsum, int nb){
  __shared__ int s[128];
  int t=threadIdx.x;
  int v = (t<nb)? bsum[t]:0;
  s[t]=v; __syncthreads();
  #pragma unroll
  for (int o=1;o<128;o<<=1){ int add=(t>=o)?s[t-o]:0; __syncthreads(); s[t]+=add; __syncthreads(); }
  if (t<nb) bsum[t] = s[t]-v;              // exclusive block offsets
}
__global__ void k_scan3(int* __restrict__ offs, const int* __restrict__ bsum,
                        int* __restrict__ cursor, int N){
  int i = blockIdx.x*256+threadIdx.x; if (i>=N) return;
  int o = offs[i] + bsum[blockIdx.x];
  offs[i]=o; cursor[i]=o;
}
__global__ void k_place(const int* __restrict__ h, const int* __restrict__ r,
                        const int* __restrict__ t, int* __restrict__ cursor,
                        int* __restrict__ eh, int* __restrict__ er, int E){
  int e = blockIdx.x*256+threadIdx.x; if (e>=E) return;
  int pos = atomicAdd(&cursor[t[e]], 1);
  eh[pos]=h[e]; er[pos]=r[e];
}

// ---------- tiny dense helpers ----------
__global__ void k_distW(const float* __restrict__ dist_emb, const float* __restrict__ W_enc,
                        float* __restrict__ distW){
  int d = blockIdx.x, j = threadIdx.x;
  const float* Wpe = W_enc + (256+4)*256;   // rows 260..275
  float s=0.f;
  #pragma unroll
  for (int p=0;p<16;p++) s += dist_emb[d*16+p]*Wpe[p*256+j];
  distW[d*256+j]=s;
}
__global__ void k_colvec(const float* __restrict__ x, const float* __restrict__ W,
                         const float* __restrict__ bias, float* __restrict__ out){
  int j = threadIdx.x; float s = bias ? bias[j] : 0.f;
  for (int k=0;k<256;k++) s += x[k]*W[k*256+j];
  out[j]=s;
}

__global__ __launch_bounds__(256)
void k_enc_fin(const float* __restrict__ enc_text, const float* __restrict__ enc_nt,
               const float* __restrict__ b_enc, const float* __restrict__ W_enc,
               const float* __restrict__ pe4, const int* __restrict__ dist,
               const float* __restrict__ topic, const float* __restrict__ amask,
               const float* __restrict__ distW, float* __restrict__ h, int N, int Ntext){
  int i = blockIdx.x, j = threadIdx.x;
  if (i>=N) return;
  const float* Wpe = W_enc + 256*256;
  float base = (i < Ntext) ? enc_text[(size_t)i*256+j] : enc_nt[j];
  float p0=pe4[i*4+0], p1=pe4[i*4+1], p2=pe4[i*4+2], p3=pe4[i*4+3];
  int d = dist[i];
  float tp = topic[i], am = amask[i];
  float v = base + b_enc[j] + Wpe[22*256+j]
          + p0*Wpe[0*256+j] + p1*Wpe[1*256+j] + p2*Wpe[2*256+j] + p3*Wpe[3*256+j]
          + distW[d*256+j]
          + tp*Wpe[20*256+j] + am*Wpe[21*256+j];
  h[(size_t)i*256+j] = fmaxf(v, 0.f);
}

// ---------- generic fp32 tiled GEMM (A may be a concat of A1|A2 along K) ----------
__global__ __launch_bounds__(256)
void k_gemm(const float* __restrict__ A1, int lda1,
            const float* __restrict__ A2, int lda2, int K1,
            const float* __restrict__ B, int ldb,
            float* __restrict__ C, int ldc,
            int M, int N, int K)
{
  __shared__ __align__(16) float As[16][132];
  __shared__ __align__(16) float Bs[16][132];
  const int tid = threadIdx.x;
  const int bm = blockIdx.y * 128, bn = blockIdx.x * 128;
  const int tx = tid & 15, ty = tid >> 4;
  float acc[8][8];
  #pragma unroll
  for (int i=0;i<8;i++)
    #pragma unroll
    for (int j=0;j<8;j++) acc[i][j]=0.f;

  for (int k0=0;k0<K;k0+=16){
    #pragma unroll
    for (int i=0;i<2;i++){
      int f = tid + i*256;
      int r = f >> 2;
      int c = (f & 3) << 2;
      int row = bm + r;
      float4 v = make_float4(0.f,0.f,0.f,0.f);
      if (row < M){
        int kc = k0 + c;
        const float* src = (kc < K1) ? (A1 + (size_t)row*lda1 + kc)
                                     : (A2 + (size_t)row*lda2 + (kc - K1));
        v = *(const float4*)src;
      }
      As[c+0][r]=v.x; As[c+1][r]=v.y; As[c+2][r]=v.z; As[c+3][r]=v.w;
    }
    #pragma unroll
    for (int i=0;i<2;i++){
      int f = tid + i*256;
      int r = f >> 5;
      int c = (f & 31) << 2;
      int col = bn + c;
      float4 v = make_float4(0.f,0.f,0.f,0.f);
      if (col < N) v = *(const float4*)(B + (size_t)(k0+r)*ldb + col);
      *(float4*)&Bs[r][c] = v;
    }
    __syncthreads();
    #pragma unroll
    for (int kk=0;kk<16;kk++){
      float a[8], b[8];
      *(float4*)&a[0] = *(const float4*)&As[kk][ty*8];
      *(float4*)&a[4] = *(const float4*)&As[kk][ty*8+4];
      *(float4*)&b[0] = *(const float4*)&Bs[kk][tx*8];
      *(float4*)&b[4] = *(const float4*)&Bs[kk][tx*8+4];
      #pragma unroll
      for (int i=0;i<8;i++)
        #pragma unroll
        for (int j=0;j<8;j++)
          acc[i][j] = fmaf(a[i], b[j], acc[i][j]);
    }
    __syncthreads();
  }
  #pragma unroll
  for (int i=0;i<8;i++){
    int row = bm + ty*8 + i;
    if (row < M){
      int col = bn + tx*8;
      if (col < N){
        *(float4*)(C + (size_t)row*ldc + col)     = *(float4*)&acc[i][0];
        *(float4*)(C + (size_t)row*ldc + col + 4) = *(float4*)&acc[i][4];
      }
    }
  }
}

// ---------- GNN aggregation: CSR gather (no atomics) ----------
__global__ __launch_bounds__(256)
void k_agg(const int* __restrict__ offs, const int* __restrict__ degi,
           const int* __restrict__ eh, const int* __restrict__ er,
           const float* __restrict__ hm, const float* __restrict__ mrel,
           float* __restrict__ agg, int N){
  int i = blockIdx.x; if (i>=N) return;
  int j = threadIdx.x;
  int start = offs[i], cnt = degi[i];
  float acc = 0.f;
  for (int k=0;k<cnt;k++){
    int h = eh[start+k], r = er[start+k];
    acc += fmaxf(hm[(size_t)h*256+j] + mrel[(size_t)r*256+j], 0.f);
  }
  agg[(size_t)i*256+j] = acc;
}

__global__ void k_update(const float* __restrict__ hin, const float* __restrict__ gpre,
                         float* __restrict__ hout /* holds upd_pre in-place */, int total){
  int i = blockIdx.x*256+threadIdx.x; if (i>=total) return;
  float g = 1.f/(1.f+expf(-gpre[i]));
  hout[i] = hin[i] + g * tanhf(hout[i]);
}

// ---------- scorer ----------
__global__ __launch_bounds__(256)
void k_score(const int* __restrict__ h_ids, const int* __restrict__ r_ids, const int* __restrict__ t_ids,
             const float* __restrict__ uh, const float* __restrict__ ut, const float* __restrict__ vr,
             const float* __restrict__ bias2, const float* __restrict__ topic,
             const int* __restrict__ aidx, const float* __restrict__ asc,
             const float* __restrict__ W1s /* rows 1024..1027 */, const float* __restrict__ W2,
             const float* __restrict__ b2, float* __restrict__ out, int E){
  __shared__ int s_ai[32]; __shared__ float s_as[32];
  if (threadIdx.x < 32){ s_ai[threadIdx.x]=aidx[threadIdx.x]; s_as[threadIdx.x]=asc[threadIdx.x]; }
  __syncthreads();
  int wid = threadIdx.x>>6, lane = threadIdx.x&63;
  int e = blockIdx.x*4 + wid; if (e>=E) return;
  int h=h_ids[e], r=r_ids[e], t=t_ids[e];
  float isA=0.f, aS=0.f;
  #pragma unroll
  for (int k=0;k<32;k++){ if (s_ai[k]==e){ isA=1.f; aS=s_as[k]; } }
  float th=topic[h], tt=topic[t];
  int c = lane*4;
  float4 acc = *(const float4*)(bias2 + c);
  float4 a = *(const float4*)(uh + (size_t)h*256 + c);
  float4 b = *(const float4*)(vr + (size_t)r*256 + c);
  float4 d = *(const float4*)(ut + (size_t)t*256 + c);
  acc.x += a.x+b.x+d.x; acc.y += a.y+b.y+d.y; acc.z += a.z+b.z+d.z; acc.w += a.w+b.w+d.w;
  float4 w0 = *(const float4*)(W1s + 0*256 + c);
  float4 w1 = *(const float4*)(W1s + 1*256 + c);
  float4 w2 = *(const float4*)(W1s + 2*256 + c);
  float4 w3 = *(const float4*)(W1s + 3*256 + c);
  acc.x += isA*w0.x + aS*w1.x + th*w2.x + tt*w3.x;
  acc.y += isA*w0.y + aS*w1.y + th*w2.y + tt*w3.y;
  acc.z += isA*w0.z + aS*w1.z + th*w2.z + tt*w3.z;
  acc.w += isA*w0.w + aS*w1.w + th*w2.w + tt*w3.w;
  acc.x=fmaxf(acc.x,0.f); acc.y=fmaxf(acc.y,0.f); acc.z=fmaxf(acc.z,0.f); acc.w=fmaxf(acc.w,0.f);
  float4 w = *(const float4*)(W2 + c);
  float p = acc.x*w.x + acc.y*w.y + acc.z*w.z + acc.w*w.w;
  p = warp_sum(p);
  if (!lane) out[e] = p + b2[0];
}

// ---------- host ----------
extern "C" void kernel_launch(void* const* d_in, const int* in_sizes, int n_in,
                              void* d_out, int out_size, void* d_ws, size_t ws_size,
                              hipStream_t stream)
{
  const int*   h_ids   = (const int*)d_in[0];
  const int*   r_ids   = (const int*)d_in[1];
  const int*   t_ids   = (const int*)d_in[2];
  const float* q       = (const float*)d_in[3];
  const float* ent     = (const float*)d_in[4];
  const float* rel     = (const float*)d_in[5];
  const int*   topicId = (const int*)d_in[6];
  const float* nontext = (const float*)d_in[9];
  const float* dist_e  = (const float*)d_in[10];
  const float* W_enc   = (const float*)d_in[11];
  const float* b_enc   = (const float*)d_in[12];
  const float* W_msg   = (const float*)d_in[13];
  const float* W_gate  = (const float*)d_in[14];
  const float* W_upd   = (const float*)d_in[15];
  const float* W_out   = (const float*)d_in[16];
  const float* W1      = (const float*)d_in[17];
  const float* b1      = (const float*)d_in[18];
  const float* W2      = (const float*)d_in[19];
  const float* b2      = (const float*)d_in[20];
  float* out = (float*)d_out;

  const int E = in_sizes[0];
  const int Ntext = in_sizes[4]/256;
  const int R = in_sizes[5]/256;
  const int NT = 500;                 // num_non_text_entities (fixed by problem)
  const int N = Ntext + NT;
  const int nTopic = in_sizes[6];

  char* ws = (char*)d_ws;
  size_t off = 0;
  auto alloc = [&](size_t bytes)->void*{
    size_t o = (off + 255) & ~(size_t)255;
    off = o + bytes;
    return (void*)(ws + o);
  };
  float* B1    = (float*)alloc((size_t)N*256*4);
  float* B2    = (float*)alloc((size_t)N*256*4);
  float* B3    = (float*)alloc((size_t)N*256*4);   // agg / u_h
  float* B4    = (float*)alloc((size_t)N*256*4);   // hm / gate_pre / u_t
  float* qe    = (float*)alloc((size_t)N*4);
  float* qr    = (float*)alloc((size_t)R*4);
  float* tri   = (float*)alloc((size_t)E*4);
  float* bmax  = (float*)alloc(256*4);
  float* thrT  = (float*)alloc(4);
  int*   cnt   = (int*)  alloc(4);
  int*   ci    = (int*)  alloc((size_t)E*4);
  float* cv    = (float*)alloc((size_t)E*4);
  int*   ai    = (int*)  alloc(32*4);
  float* as    = (float*)alloc(32*4);
  float* topic = (float*)alloc((size_t)N*4);
  float* amask = (float*)alloc((size_t)N*4);
  float* degt  = (float*)alloc((size_t)N*4);
  float* degh  = (float*)alloc((size_t)N*4);
  float* sA    = (float*)alloc((size_t)N*4);
  float* sB    = (float*)alloc((size_t)N*4);
  float* pe4   = (float*)alloc((size_t)N*16);
  int*   dist  = (int*)  alloc((size_t)N*4);
  int*   c1    = (int*)  alloc((size_t)N*4);
  int*   c2    = (int*)  alloc((size_t)N*4);
  float* distW = (float*)alloc(5*256*4);
  float* encnt = (float*)alloc(256*4);
  float* mrel  = (float*)alloc((size_t)R*256*4);
  float* vrel  = (float*)alloc((size_t)R*256*4);
  float* bias2 = (float*)alloc(256*4);
  // CSR (dest-bucketed edges)
  int*   degi  = (int*)  alloc((size_t)N*4);
  int*   offs  = (int*)  alloc((size_t)N*4);
  int*   bsum  = (int*)  alloc(128*4);
  int*   cursor= (int*)  alloc((size_t)N*4);
  int*   eh    = (int*)  alloc((size_t)E*4);
  int*   er    = (int*)  alloc((size_t)E*4);
  (void)ws_size; (void)n_in; (void)out_size;

  // ---- zero init ----
  hipMemsetAsync(cnt,   0, 4, stream);
  hipMemsetAsync(topic, 0, (size_t)N*4, stream);
  hipMemsetAsync(amask, 0, (size_t)N*4, stream);
  hipMemsetAsync(degt,  0, (size_t)N*4, stream);
  hipMemsetAsync(degh,  0, (size_t)N*4, stream);
  hipMemsetAsync(degi,  0, (size_t)N*4, stream);

  // ---- triple scores + top-32 ----
  k_rowdot<<<CDIV(N,4),256,0,stream>>>(ent, nontext, q, qe, N, Ntext);
  k_rowdot<<<CDIV(R,4),256,0,stream>>>(rel, nontext, q, qr, R, R);
  k_tri<<<CDIV(E,256),256,0,stream>>>(h_ids, r_ids, t_ids, qe, qr, tri, E);
  k_bmax<<<256,256,0,stream>>>(tri, bmax, E);
  k_thresh<<<1,256,0,stream>>>(bmax, thrT);
  k_compact<<<CDIV(E,256),256,0,stream>>>(tri, thrT, cnt, ci, cv, E);
  k_final32<<<1,256,0,stream>>>(ci, cv, cnt, ai, as);

  // ---- topic / anchor masks / degrees ----
  k_topic<<<1,64,0,stream>>>(topicId, topic, nTopic);
  k_amask<<<1,32,0,stream>>>(ai, h_ids, t_ids, amask);
  k_deg<<<CDIV(E,256),256,0,stream>>>(h_ids, t_ids, degt, degh, E);

  // ---- CSR build (by destination t) ----
  {
    int nb = CDIV(N,256);
    k_hist <<<CDIV(E,256),256,0,stream>>>(t_ids, degi, E);
    k_scan1<<<nb,256,0,stream>>>(degi, offs, bsum, N);
    k_scan2<<<1,128,0,stream>>>(bsum, nb);
    k_scan3<<<nb,256,0,stream>>>(offs, bsum, cursor, N);
    k_place<<<CDIV(E,256),256,0,stream>>>(h_ids, r_ids, t_ids, cursor, eh, er, E);
  }

  // ---- DDE label propagation (2 fwd + 2 rev) ----
  {
    float* cur=sA; float* nxt=sB;
    k_copyf<<<CDIV(N,256),256,0,stream>>>(topic, cur, N);
    for (int r0=0;r0<2;r0++){
      hipMemsetAsync(nxt, 0, (size_t)N*4, stream);
      k_dde_edge<<<CDIV(E,256),256,0,stream>>>(h_ids, t_ids, cur, nxt, E);
      k_dde_div<<<CDIV(N,256),256,0,stream>>>(nxt, degt, pe4, r0, N);
      float* tmp=cur; cur=nxt; nxt=tmp;
    }
    k_copyf<<<CDIV(N,256),256,0,stream>>>(topic, cur, N);
    for (int r0=0;r0<2;r0++){
      hipMemsetAsync(nxt, 0, (size_t)N*4, stream);
      k_dde_edge<<<CDIV(E,256),256,0,stream>>>(t_ids, h_ids, cur, nxt, E);
      k_dde_div<<<CDIV(N,256),256,0,stream>>>(nxt, degh, pe4, 2+r0, N);
      float* tmp=cur; cur=nxt; nxt=tmp;
    }
  }

  // ---- bounded BFS from anchor endpoints ----
  k_dist_init<<<CDIV(N,256),256,0,stream>>>(amask, dist, N);
  for (int it=0; it<3; it++){
    k_fill2<<<CDIV(N,256),256,0,stream>>>(c1, c2, 4, N);
    k_bfs_edge<<<CDIV(E,256),256,0,stream>>>(h_ids, t_ids, dist, c1, c2, E);
    k_bfs_comb<<<CDIV(N,256),256,0,stream>>>(dist, c1, c2, N);
  }

  // ---- encoder ----
  k_distW<<<5,256,0,stream>>>(dist_e, W_enc, distW);
  k_colvec<<<1,256,0,stream>>>(nontext, W_enc, nullptr, encnt);
  k_gemm<<<dim3(2,CDIV(Ntext,128)),256,0,stream>>>(ent,256, ent,256, 256, W_enc,256, B2,256, Ntext,256,256);
  k_enc_fin<<<N,256,0,stream>>>(B2, encnt, b_enc, W_enc, pe4, dist, topic, amask, distW, B1, N, Ntext);

  // ---- 2-layer gated GNN ----
  for (int l=0;l<2;l++){
    const float* Wm = W_msg  + (size_t)l*512*256;
    const float* Wg = W_gate + (size_t)l*512*256;
    const float* Wu = W_upd  + (size_t)l*256*256;
    float* hin  = l ? B2 : B1;
    float* hout = l ? B1 : B2;
    // mrel = rel @ Wm[256:512]
    k_gemm<<<dim3(2,CDIV(R,128)),256,0,stream>>>(rel,256, rel,256, 256, Wm+256*256,256, mrel,256, R,256,256);
    // hm = h @ Wm[0:256]  -> B4
    k_gemm<<<dim3(2,CDIV(N,128)),256,0,stream>>>(hin,256, hin,256, 256, Wm,256, B4,256, N,256,256);
    // agg = gather-sum relu(hm[h]+mrel[r]) over incoming edges of t  -> B3
    k_agg<<<N,256,0,stream>>>(offs, degi, eh, er, B4, mrel, B3, N);
    // gate_pre = [h,agg] @ Wg -> B4 ; upd_pre = agg @ Wu -> hout
    k_gemm<<<dim3(2,CDIV(N,128)),256,0,stream>>>(hin,256, B3,256, 256, Wg,256, B4,256, N,256,512);
    k_gemm<<<dim3(2,CDIV(N,128)),256,0,stream>>>(B3,256, B3,256, 256, Wu,256, hout,256, N,256,256);
    // hout = hin + sigmoid(gate_pre)*tanh(upd_pre)
    k_update<<<CDIV(N*256,256),256,0,stream>>>(hin, B4, hout, N*256);
  }

  // ---- output head: h_final = h @ W_out (h is in B1) ----
  k_gemm<<<dim3(2,CDIV(N,128)),256,0,stream>>>(B1,256, B1,256, 256, W_out,256, B2,256, N,256,256);
  // u_h = hf @ W1[256:512] -> B3 ; u_t = hf @ W1[768:1024] -> B4 ; vrel = rel @ W1[512:768]
  k_gemm<<<dim3(2,CDIV(N,128)),256,0,stream>>>(B2,256, B2,256, 256, W1+(size_t)256*256,256, B3,256, N,256,256);
  k_gemm<<<dim3(2,CDIV(N,128)),256,0,stream>>>(B2,256, B2,256, 256, W1+(size_t)768*256,256, B4,256, N,256,256);
  k_gemm<<<dim3(2,CDIV(R,128)),256,0,stream>>>(rel,256, rel,256, 256, W1+(size_t)512*256,256, vrel,256, R,256,256);
  // bias2 = b1 + q @ W1[0:256]
  k_colvec<<<1,256,0,stream>>>(q, W1, b1, bias2);

  // ---- final scorer over all edges ----
  k_score<<<CDIV(E,4),256,0,stream>>>(h_ids, r_ids, t_ids, B3, B4, vrel, bias2, topic,
                                      ai, as, W1+(size_t)1024*256, W2, b2, out, E);
}

// Round 3
// 766.418 us; speedup vs baseline: 3.3278x; 1.7283x over previous
//
#include <hip/hip_runtime.h>
#include <math.h>

#define CDIV(a,b) (((a)+(b)-1)/(b))

typedef short short8 __attribute__((ext_vector_type(8)));
typedef float f32x4  __attribute__((ext_vector_type(4)));

__device__ __forceinline__ float warp_sum(float v){
  #pragma unroll
  for (int o=32;o;o>>=1) v += __shfl_down(v,o);
  return v;
}

__device__ __forceinline__ unsigned short f2bf(float f){
  unsigned u = __float_as_uint(f);
  unsigned r = 0x7fffu + ((u>>16)&1u);
  return (unsigned short)((u + r)>>16);
}

// ---------- small vector kernels ----------
__global__ __launch_bounds__(256)
void k_rowdot(const float* __restrict__ A, const float* __restrict__ alt,
              const float* __restrict__ q, float* __restrict__ out,
              int rows, int textRows){
  int wid = threadIdx.x>>6, lane = threadIdx.x&63;
  int row = blockIdx.x*4 + wid;
  if (row >= rows) return;
  const float* src = (row < textRows) ? (A + (size_t)row*256) : alt;
  float4 a = *(const float4*)(src + lane*4);
  float4 b = *(const float4*)(q + lane*4);
  float s = a.x*b.x + a.y*b.y + a.z*b.z + a.w*b.w;
  s = warp_sum(s);
  if (!lane) out[row] = s;
}

__global__ void k_tri(const int* __restrict__ h, const int* __restrict__ r,
                      const int* __restrict__ t, const float* __restrict__ qe,
                      const float* __restrict__ qr, float* __restrict__ tri, int E){
  int e = blockIdx.x*256 + threadIdx.x; if (e>=E) return;
  tri[e] = qe[h[e]] + qr[r[e]] + qe[t[e]];
}

// ---------- top-32 (exact, with jax tie-break: lower index first) ----------
__global__ void k_bmax(const float* __restrict__ tri, float* __restrict__ bmax, int E){
  __shared__ float red[256];
  int chunk = CDIV(E, (int)gridDim.x);
  int lo = blockIdx.x*chunk, hi = min(E, lo+chunk);
  float m = -INFINITY;
  for (int i=lo+threadIdx.x; i<hi; i+=256) m = fmaxf(m, tri[i]);
  red[threadIdx.x]=m; __syncthreads();
  for (int s=128;s;s>>=1){ if ((int)threadIdx.x<s) red[threadIdx.x]=fmaxf(red[threadIdx.x],red[threadIdx.x+s]); __syncthreads(); }
  if (!threadIdx.x) bmax[blockIdx.x]=red[0];
}

__global__ void k_thresh(const float* __restrict__ bmax, float* __restrict__ thrT){
  __shared__ float v[256];
  __shared__ float red[256];
  __shared__ int who;
  int t = threadIdx.x;
  v[t] = bmax[t];
  __syncthreads();
  for (int it=0; it<32; it++){
    red[t]=v[t]; __syncthreads();
    for (int s=128;s;s>>=1){ if (t<s) red[t]=fmaxf(red[t],red[t+s]); __syncthreads(); }
    float m = red[0];
    if (it==31 && t==0) thrT[0]=m;
    if (t==0) who = 256;
    __syncthreads();
    if (v[t]==m) atomicMin(&who, t);
    __syncthreads();
    if (t==who) v[t] = -INFINITY;
    __syncthreads();
  }
}

__global__ void k_compact(const float* __restrict__ tri, const float* __restrict__ thrT,
                          int* __restrict__ cnt, int* __restrict__ ci, float* __restrict__ cv, int E){
  int e = blockIdx.x*256 + threadIdx.x; if (e>=E) return;
  float v = tri[e];
  if (v >= thrT[0]){
    int p = atomicAdd(cnt, 1);
    ci[p]=e; cv[p]=v;
  }
}

__global__ __launch_bounds__(256)
void k_final32(const int* __restrict__ ci, float* __restrict__ cv, const int* __restrict__ cnt,
               int* __restrict__ ai, float* __restrict__ as){
  int C = *cnt;
  int t = threadIdx.x;
  __shared__ float rv[256]; __shared__ int ri[256]; __shared__ int rp[256];
  for (int it=0; it<32; it++){
    float bv=-INFINITY; int bi=0x7fffffff; int bp=-1;
    for (int p=t; p<C; p+=256){
      float v = cv[p]; int i = ci[p];
      if (v>bv || (v==bv && i<bi)){ bv=v; bi=i; bp=p; }
    }
    rv[t]=bv; ri[t]=bi; rp[t]=bp; __syncthreads();
    for (int s=128;s;s>>=1){
      if (t<s){
        if (rv[t+s]>rv[t] || (rv[t+s]==rv[t] && ri[t+s]<ri[t])){ rv[t]=rv[t+s]; ri[t]=ri[t+s]; rp[t]=rp[t+s]; }
      }
      __syncthreads();
    }
    if (t==0){ ai[it]=ri[0]; as[it]=rv[0]; cv[rp[0]] = -INFINITY; }
    __syncthreads();
  }
}

// ---------- graph PE kernels ----------
__global__ void k_topic(const int* __restrict__ ids, float* __restrict__ topic, int n){
  if ((int)threadIdx.x < n) topic[ids[threadIdx.x]] = 1.f;
}
__global__ void k_amask(const int* __restrict__ ai, const int* __restrict__ h,
                        const int* __restrict__ t, float* __restrict__ amask){
  int k = threadIdx.x; if (k>=32) return;
  int e = ai[k];
  amask[h[e]] = 1.f;
  amask[t[e]] = 1.f;
}
__global__ void k_deg(const int* __restrict__ h, const int* __restrict__ t,
                      float* __restrict__ degt, float* __restrict__ degh, int E){
  int e = blockIdx.x*256+threadIdx.x; if (e>=E) return;
  atomicAdd(&degt[t[e]], 1.f);
  atomicAdd(&degh[h[e]], 1.f);
}
__global__ void k_copyf(const float* __restrict__ a, float* __restrict__ b, int n){
  int i = blockIdx.x*256+threadIdx.x; if (i<n) b[i]=a[i];
}
__global__ void k_dde_edge(const int* __restrict__ src, const int* __restrict__ dst,
                           const float* __restrict__ s, float* __restrict__ sn, int E){
  int e = blockIdx.x*256+threadIdx.x; if (e>=E) return;
  atomicAdd(&sn[dst[e]], s[src[e]]);
}
__global__ void k_dde_div(float* __restrict__ sn, const float* __restrict__ deg,
                          float* __restrict__ pe4, int col, int N){
  int i = blockIdx.x*256+threadIdx.x; if (i>=N) return;
  float v = sn[i] / fmaxf(deg[i], 1.f);
  sn[i] = v;
  pe4[i*4+col] = v;
}
__global__ void k_dist_init(const float* __restrict__ amask, int* __restrict__ dist, int N){
  int i = blockIdx.x*256+threadIdx.x; if (i>=N) return;
  dist[i] = (amask[i] > 0.f) ? 0 : 4;
}
__global__ void k_fill2(int* __restrict__ c1, int* __restrict__ c2, int val, int N){
  int i = blockIdx.x*256+threadIdx.x; if (i>=N) return;
  c1[i]=val; c2[i]=val;
}
__global__ void k_bfs_edge(const int* __restrict__ h, const int* __restrict__ t,
                           const int* __restrict__ dist, int* __restrict__ c1, int* __restrict__ c2, int E){
  int e = blockIdx.x*256+threadIdx.x; if (e>=E) return;
  int hh=h[e], tt=t[e];
  atomicMin(&c1[tt], dist[hh]+1);
  atomicMin(&c2[hh], dist[tt]+1);
}
__global__ void k_bfs_comb(int* __restrict__ dist, const int* __restrict__ c1, const int* __restrict__ c2, int N){
  int i = blockIdx.x*256+threadIdx.x; if (i>=N) return;
  dist[i] = min(dist[i], min(c1[i], c2[i]));
}

// ---------- CSR build (bucket edges by destination t) ----------
__global__ void k_hist(const int* __restrict__ t, int* __restrict__ degi, int E){
  int e = blockIdx.x*256+threadIdx.x; if (e>=E) return;
  atomicAdd(&degi[t[e]], 1);
}
__global__ void k_scan1(const int* __restrict__ deg, int* __restrict__ offs,
                        int* __restrict__ bsum, int N){
  __shared__ int s[256];
  int i = blockIdx.x*256 + threadIdx.x;
  int v = (i<N) ? deg[i] : 0;
  s[threadIdx.x] = v; __syncthreads();
  #pragma unroll
  for (int o=1;o<256;o<<=1){
    int add = (threadIdx.x>=(unsigned)o) ? s[threadIdx.x-o] : 0; __syncthreads();
    s[threadIdx.x] += add; __syncthreads();
  }
  if (i<N) offs[i] = s[threadIdx.x] - v;   // exclusive
  if (threadIdx.x==255) bsum[blockIdx.x] = s[255];
}
__global__ void k_scan2(int* __restrict__ bsum, int nb){
  __shared__ int s[128];
  int t=threadIdx.x;
  int v = (t<nb)? bsum[t]:0;
  s[t]=v; __syncthreads();
  #pragma unroll
  for (int o=1;o<128;o<<=1){ int add=(t>=o)?s[t-o]:0; __syncthreads(); s[t]+=add; __syncthreads(); }
  if (t<nb) bsum[t] = s[t]-v;              // exclusive block offsets
}
__global__ void k_scan3(int* __restrict__ offs, const int* __restrict__ bsum,
                        int* __restrict__ cursor, int N){
  int i = blockIdx.x*256+threadIdx.x; if (i>=N) return;
  int o = offs[i] + bsum[blockIdx.x];
  offs[i]=o; cursor[i]=o;
}
__global__ void k_place(const int* __restrict__ h, const int* __restrict__ r,
                        const int* __restrict__ t, int* __restrict__ cursor,
                        int* __restrict__ eh, int* __restrict__ er, int E){
  int e = blockIdx.x*256+threadIdx.x; if (e>=E) return;
  int pos = atomicAdd(&cursor[t[e]], 1);
  eh[pos]=h[e]; er[pos]=r[e];
}

// ---------- tiny dense helpers ----------
__global__ void k_distW(const float* __restrict__ dist_emb, const float* __restrict__ W_enc,
                        float* __restrict__ distW){
  int d = blockIdx.x, j = threadIdx.x;
  const float* Wpe = W_enc + (256+4)*256;   // rows 260..275
  float s=0.f;
  #pragma unroll
  for (int p=0;p<16;p++) s += dist_emb[d*16+p]*Wpe[p*256+j];
  distW[d*256+j]=s;
}
__global__ void k_colvec(const float* __restrict__ x, const float* __restrict__ W,
                         const float* __restrict__ bias, float* __restrict__ out){
  int j = threadIdx.x; float s = bias ? bias[j] : 0.f;
  for (int k=0;k<256;k++) s += x[k]*W[k*256+j];
  out[j]=s;
}

__global__ __launch_bounds__(256)
void k_enc_fin(const float* __restrict__ enc_text, const float* __restrict__ enc_nt,
               const float* __restrict__ b_enc, const float* __restrict__ W_enc,
               const float* __restrict__ pe4, const int* __restrict__ dist,
               const float* __restrict__ topic, const float* __restrict__ amask,
               const float* __restrict__ distW, float* __restrict__ h, int N, int Ntext){
  int i = blockIdx.x, j = threadIdx.x;
  if (i>=N) return;
  const float* Wpe = W_enc + 256*256;
  float base = (i < Ntext) ? enc_text[(size_t)i*256+j] : enc_nt[j];
  float p0=pe4[i*4+0], p1=pe4[i*4+1], p2=pe4[i*4+2], p3=pe4[i*4+3];
  int d = dist[i];
  float tp = topic[i], am = amask[i];
  float v = base + b_enc[j] + Wpe[22*256+j]
          + p0*Wpe[0*256+j] + p1*Wpe[1*256+j] + p2*Wpe[2*256+j] + p3*Wpe[3*256+j]
          + distW[d*256+j]
          + tp*Wpe[20*256+j] + am*Wpe[21*256+j];
  h[(size_t)i*256+j] = fmaxf(v, 0.f);
}

// ---------- B pack: fp32 [K][256] (one or two sources) -> bf16 MFMA-frag order ----------
// Frag f=(ks,nt): lane l holds B[ks*32 + 8*(l>>4)+i][nt*16 + (l&15)], i=0..7
__global__ void k_pack(const float* __restrict__ src0, const float* __restrict__ src1,
                       int split, unsigned short* __restrict__ Bp, int Ncols){
  int nt16 = Ncols/16;
  int f = blockIdx.x;
  int ks = f / nt16, nt = f % nt16;
  int lane = threadIdx.x;
  int k = ks*32 + 8*(lane>>4);
  int n = nt*16 + (lane&15);
  const float* s; int col;
  if (n < split){ s = src0; col = n; } else { s = src1; col = n - split; }
  unsigned short v[8];
  #pragma unroll
  for (int i=0;i<8;i++) v[i] = f2bf(s[(size_t)(k+i)*256 + col]);
  unsigned short* dst = Bp + ((size_t)f*64 + lane)*8;
  *(uint4*)dst = *(uint4*)v;
}

// ---------- MFMA bf16 GEMM: C[M][NCOLS] = A[M][K(<=512)] @ Bpacked ----------
// A is fp32 (row stride 256), converted to bf16 in-register. K via A1|A2 concat (K1 split).
// 256 threads = 4 waves as 2x2: wave rows wr*16, cols wc*(NCOLS/2).
template<int NCOLS, bool GATED>
__global__ __launch_bounds__(256)
void k_bgemm(const float* __restrict__ A1, const float* __restrict__ A2, int K1,
             const unsigned short* __restrict__ Bp, float* __restrict__ C,
             const float* __restrict__ hin, const float* __restrict__ gpre,
             int M, int K)
{
  constexpr int NT16 = NCOLS/16;
  constexpr int NREP = NCOLS/32;       // frags per wave (half of N / 16)
  const int tid  = threadIdx.x;
  const int lane = tid & 63;
  const int w    = tid >> 6;
  const int wr   = w >> 1, wc = w & 1;
  const int row0 = blockIdx.x*32 + wr*16;
  const int lrow = lane & 15;
  const int kc   = lane >> 4;          // 0..3
  int arow = row0 + lrow;
  if (arow >= M) arow = M-1;

  f32x4 acc[NREP];
  #pragma unroll
  for (int n=0;n<NREP;n++) acc[n] = (f32x4){0.f,0.f,0.f,0.f};

  const int ksteps = K/32;
  for (int ks=0; ks<ksteps; ks++){
    int k0 = ks*32;
    const float* Asrc = (k0 < K1) ? A1 : A2;
    int kk = (k0 < K1) ? k0 : (k0 - K1);
    const float* ap = Asrc + (size_t)arow*256 + kk + kc*8;
    float4 a0 = *(const float4*)ap;
    float4 a1 = *(const float4*)(ap+4);
    short8 af;
    af[0]=(short)f2bf(a0.x); af[1]=(short)f2bf(a0.y); af[2]=(short)f2bf(a0.z); af[3]=(short)f2bf(a0.w);
    af[4]=(short)f2bf(a1.x); af[5]=(short)f2bf(a1.y); af[6]=(short)f2bf(a1.z); af[7]=(short)f2bf(a1.w);
    const unsigned short* bp = Bp + ((size_t)(ks*NT16 + wc*NREP)*64 + lane)*8;
    #pragma unroll
    for (int n=0;n<NREP;n++){
      short8 bf = *(const short8*)(bp + (size_t)n*64*8);
      acc[n] = __builtin_amdgcn_mfma_f32_16x16x32_bf16(af, bf, acc[n], 0, 0, 0);
    }
  }

  // store: lane holds D rows 4*kc+r (within wave's 16-row tile), col lrow of each 16-col frag
  #pragma unroll
  for (int r=0;r<4;r++){
    int orow = row0 + 4*kc + r;
    if (orow >= M) continue;
    #pragma unroll
    for (int n=0;n<NREP;n++){
      int col = wc*(NCOLS/2) + n*16 + lrow;
      float v = acc[n][r];
      if (GATED){
        size_t idx = (size_t)orow*256 + col;
        float g = 1.f/(1.f+expf(-gpre[idx]));
        v = hin[idx] + g * tanhf(v);
      }
      C[(size_t)orow*NCOLS + col] = v;
    }
  }
}

// ---------- GNN aggregation: CSR gather (no atomics) ----------
__global__ __launch_bounds__(256)
void k_agg(const int* __restrict__ offs, const int* __restrict__ degi,
           const int* __restrict__ eh, const int* __restrict__ er,
           const float* __restrict__ hm, const float* __restrict__ mrel,
           float* __restrict__ agg, int N){
  int i = blockIdx.x; if (i>=N) return;
  int j = threadIdx.x;
  int start = offs[i], cnt = degi[i];
  float acc = 0.f;
  for (int k=0;k<cnt;k++){
    int h = eh[start+k], r = er[start+k];
    acc += fmaxf(hm[(size_t)h*256+j] + mrel[(size_t)r*256+j], 0.f);
  }
  agg[(size_t)i*256+j] = acc;
}

// ---------- scorer (UHT holds [uh | ut] with row stride 512) ----------
__global__ __launch_bounds__(256)
void k_score(const int* __restrict__ h_ids, const int* __restrict__ r_ids, const int* __restrict__ t_ids,
             const float* __restrict__ UHT, const float* __restrict__ vr,
             const float* __restrict__ bias2, const float* __restrict__ topic,
             const int* __restrict__ aidx, const float* __restrict__ asc,
             const float* __restrict__ W1s /* rows 1024..1027 */, const float* __restrict__ W2,
             const float* __restrict__ b2, float* __restrict__ out, int E){
  __shared__ int s_ai[32]; __shared__ float s_as[32];
  if (threadIdx.x < 32){ s_ai[threadIdx.x]=aidx[threadIdx.x]; s_as[threadIdx.x]=asc[threadIdx.x]; }
  __syncthreads();
  int wid = threadIdx.x>>6, lane = threadIdx.x&63;
  int e = blockIdx.x*4 + wid; if (e>=E) return;
  int h=h_ids[e], r=r_ids[e], t=t_ids[e];
  float isA=0.f, aS=0.f;
  #pragma unroll
  for (int k=0;k<32;k++){ if (s_ai[k]==e){ isA=1.f; aS=s_as[k]; } }
  float th=topic[h], tt=topic[t];
  int c = lane*4;
  float4 acc = *(const float4*)(bias2 + c);
  float4 a = *(const float4*)(UHT + (size_t)h*512 + c);
  float4 b = *(const float4*)(vr + (size_t)r*256 + c);
  float4 d = *(const float4*)(UHT + (size_t)t*512 + 256 + c);
  acc.x += a.x+b.x+d.x; acc.y += a.y+b.y+d.y; acc.z += a.z+b.z+d.z; acc.w += a.w+b.w+d.w;
  float4 w0 = *(const float4*)(W1s + 0*256 + c);
  float4 w1 = *(const float4*)(W1s + 1*256 + c);
  float4 w2 = *(const float4*)(W1s + 2*256 + c);
  float4 w3 = *(const float4*)(W1s + 3*256 + c);
  acc.x += isA*w0.x + aS*w1.x + th*w2.x + tt*w3.x;
  acc.y += isA*w0.y + aS*w1.y + th*w2.y + tt*w3.y;
  acc.z += isA*w0.z + aS*w1.z + th*w2.z + tt*w3.z;
  acc.w += isA*w0.w + aS*w1.w + th*w2.w + tt*w3.w;
  acc.x=fmaxf(acc.x,0.f); acc.y=fmaxf(acc.y,0.f); acc.z=fmaxf(acc.z,0.f); acc.w=fmaxf(acc.w,0.f);
  float4 w = *(const float4*)(W2 + c);
  float p = acc.x*w.x + acc.y*w.y + acc.z*w.z + acc.w*w.w;
  p = warp_sum(p);
  if (!lane) out[e] = p + b2[0];
}

// ---------- host ----------
extern "C" void kernel_launch(void* const* d_in, const int* in_sizes, int n_in,
                              void* d_out, int out_size, void* d_ws, size_t ws_size,
                              hipStream_t stream)
{
  const int*   h_ids   = (const int*)d_in[0];
  const int*   r_ids   = (const int*)d_in[1];
  const int*   t_ids   = (const int*)d_in[2];
  const float* q       = (const float*)d_in[3];
  const float* ent     = (const float*)d_in[4];
  const float* rel     = (const float*)d_in[5];
  const int*   topicId = (const int*)d_in[6];
  const float* nontext = (const float*)d_in[9];
  const float* dist_e  = (const float*)d_in[10];
  const float* W_enc   = (const float*)d_in[11];
  const float* b_enc   = (const float*)d_in[12];
  const float* W_msg   = (const float*)d_in[13];
  const float* W_gate  = (const float*)d_in[14];
  const float* W_upd   = (const float*)d_in[15];
  const float* W_out   = (const float*)d_in[16];
  const float* W1      = (const float*)d_in[17];
  const float* b1      = (const float*)d_in[18];
  const float* W2      = (const float*)d_in[19];
  const float* b2      = (const float*)d_in[20];
  float* out = (float*)d_out;

  const int E = in_sizes[0];
  const int Ntext = in_sizes[4]/256;
  const int R = in_sizes[5]/256;
  const int NT = 500;                 // num_non_text_entities (fixed by problem)
  const int N = Ntext + NT;
  const int nTopic = in_sizes[6];
  const int BIGK1 = 1<<28;

  char* ws = (char*)d_ws;
  size_t off = 0;
  auto alloc = [&](size_t bytes)->void*{
    size_t o = (off + 255) & ~(size_t)255;
    off = o + bytes;
    return (void*)(ws + o);
  };
  float* B1    = (float*)alloc((size_t)N*256*4);
  float* B2    = (float*)alloc((size_t)N*256*4);
  float* B3    = (float*)alloc((size_t)N*256*4);   // agg ; later UHT low half
  float* B4    = (float*)alloc((size_t)N*256*4);   // hm / gate_pre ; later UHT high half
  float* qe    = (float*)alloc((size_t)N*4);
  float* qr    = (float*)alloc((size_t)R*4);
  float* tri   = (float*)alloc((size_t)E*4);
  float* bmax  = (float*)alloc(256*4);
  float* thrT  = (float*)alloc(4);
  int*   cnt   = (int*)  alloc(4);
  int*   ci    = (int*)  alloc((size_t)E*4);
  float* cv    = (float*)alloc((size_t)E*4);
  int*   ai    = (int*)  alloc(32*4);
  float* as    = (float*)alloc(32*4);
  float* topic = (float*)alloc((size_t)N*4);
  float* amask = (float*)alloc((size_t)N*4);
  float* degt  = (float*)alloc((size_t)N*4);
  float* degh  = (float*)alloc((size_t)N*4);
  float* sA    = (float*)alloc((size_t)N*4);
  float* sB    = (float*)alloc((size_t)N*4);
  float* pe4   = (float*)alloc((size_t)N*16);
  int*   dist  = (int*)  alloc((size_t)N*4);
  int*   c1    = (int*)  alloc((size_t)N*4);
  int*   c2    = (int*)  alloc((size_t)N*4);
  float* distW = (float*)alloc(5*256*4);
  float* encnt = (float*)alloc(256*4);
  float* mrel  = (float*)alloc((size_t)R*256*4);
  float* vrel  = (float*)alloc((size_t)R*256*4);
  float* bias2 = (float*)alloc(256*4);
  // CSR (dest-bucketed edges)
  int*   degi  = (int*)  alloc((size_t)N*4);
  int*   offs  = (int*)  alloc((size_t)N*4);
  int*   bsum  = (int*)  alloc(128*4);
  int*   cursor= (int*)  alloc((size_t)N*4);
  int*   eh    = (int*)  alloc((size_t)E*4);
  int*   er    = (int*)  alloc((size_t)E*4);
  // packed bf16 weights
  unsigned short* pbWenc = (unsigned short*)alloc((size_t)256*256*2);
  unsigned short* pbWmT0 = (unsigned short*)alloc((size_t)256*256*2);
  unsigned short* pbWmT1 = (unsigned short*)alloc((size_t)256*256*2);
  unsigned short* pbWmB0 = (unsigned short*)alloc((size_t)256*256*2);
  unsigned short* pbWmB1 = (unsigned short*)alloc((size_t)256*256*2);
  unsigned short* pbWg0  = (unsigned short*)alloc((size_t)512*256*2);
  unsigned short* pbWg1  = (unsigned short*)alloc((size_t)512*256*2);
  unsigned short* pbWu0  = (unsigned short*)alloc((size_t)256*256*2);
  unsigned short* pbWu1  = (unsigned short*)alloc((size_t)256*256*2);
  unsigned short* pbWout = (unsigned short*)alloc((size_t)256*256*2);
  unsigned short* pbW1ht = (unsigned short*)alloc((size_t)256*512*2);
  unsigned short* pbW1r  = (unsigned short*)alloc((size_t)256*256*2);
  (void)ws_size; (void)n_in; (void)out_size;

  // ---- zero init ----
  hipMemsetAsync(cnt,   0, 4, stream);
  hipMemsetAsync(topic, 0, (size_t)N*4, stream);
  hipMemsetAsync(amask, 0, (size_t)N*4, stream);
  hipMemsetAsync(degt,  0, (size_t)N*4, stream);
  hipMemsetAsync(degh,  0, (size_t)N*4, stream);
  hipMemsetAsync(degi,  0, (size_t)N*4, stream);

  // ---- pack all GEMM B operands to bf16 frag order (L2-resident) ----
  k_pack<<<128,64,0,stream>>>(W_enc, W_enc, 256, pbWenc, 256);
  k_pack<<<128,64,0,stream>>>(W_msg,               W_msg, 256, pbWmT0, 256);
  k_pack<<<128,64,0,stream>>>(W_msg+(size_t)512*256, W_msg, 256, pbWmT1, 256);
  k_pack<<<128,64,0,stream>>>(W_msg+(size_t)256*256, W_msg, 256, pbWmB0, 256);
  k_pack<<<128,64,0,stream>>>(W_msg+(size_t)768*256, W_msg, 256, pbWmB1, 256);
  k_pack<<<256,64,0,stream>>>(W_gate,               W_gate, 256, pbWg0, 256);
  k_pack<<<256,64,0,stream>>>(W_gate+(size_t)512*256, W_gate, 256, pbWg1, 256);
  k_pack<<<128,64,0,stream>>>(W_upd,               W_upd, 256, pbWu0, 256);
  k_pack<<<128,64,0,stream>>>(W_upd+(size_t)256*256, W_upd, 256, pbWu1, 256);
  k_pack<<<128,64,0,stream>>>(W_out, W_out, 256, pbWout, 256);
  k_pack<<<256,64,0,stream>>>(W1+(size_t)256*256, W1+(size_t)768*256, 256, pbW1ht, 512);
  k_pack<<<128,64,0,stream>>>(W1+(size_t)512*256, W1, 256, pbW1r, 256);

  // ---- triple scores + top-32 ----
  k_rowdot<<<CDIV(N,4),256,0,stream>>>(ent, nontext, q, qe, N, Ntext);
  k_rowdot<<<CDIV(R,4),256,0,stream>>>(rel, nontext, q, qr, R, R);
  k_tri<<<CDIV(E,256),256,0,stream>>>(h_ids, r_ids, t_ids, qe, qr, tri, E);
  k_bmax<<<256,256,0,stream>>>(tri, bmax, E);
  k_thresh<<<1,256,0,stream>>>(bmax, thrT);
  k_compact<<<CDIV(E,256),256,0,stream>>>(tri, thrT, cnt, ci, cv, E);
  k_final32<<<1,256,0,stream>>>(ci, cv, cnt, ai, as);

  // ---- topic / anchor masks / degrees ----
  k_topic<<<1,64,0,stream>>>(topicId, topic, nTopic);
  k_amask<<<1,32,0,stream>>>(ai, h_ids, t_ids, amask);
  k_deg<<<CDIV(E,256),256,0,stream>>>(h_ids, t_ids, degt, degh, E);

  // ---- CSR build (by destination t) ----
  {
    int nb = CDIV(N,256);
    k_hist <<<CDIV(E,256),256,0,stream>>>(t_ids, degi, E);
    k_scan1<<<nb,256,0,stream>>>(degi, offs, bsum, N);
    k_scan2<<<1,128,0,stream>>>(bsum, nb);
    k_scan3<<<nb,256,0,stream>>>(offs, bsum, cursor, N);
    k_place<<<CDIV(E,256),256,0,stream>>>(h_ids, r_ids, t_ids, cursor, eh, er, E);
  }

  // ---- DDE label propagation (2 fwd + 2 rev) ----
  {
    float* cur=sA; float* nxt=sB;
    k_copyf<<<CDIV(N,256),256,0,stream>>>(topic, cur, N);
    for (int r0=0;r0<2;r0++){
      hipMemsetAsync(nxt, 0, (size_t)N*4, stream);
      k_dde_edge<<<CDIV(E,256),256,0,stream>>>(h_ids, t_ids, cur, nxt, E);
      k_dde_div<<<CDIV(N,256),256,0,stream>>>(nxt, degt, pe4, r0, N);
      float* tmp=cur; cur=nxt; nxt=tmp;
    }
    k_copyf<<<CDIV(N,256),256,0,stream>>>(topic, cur, N);
    for (int r0=0;r0<2;r0++){
      hipMemsetAsync(nxt, 0, (size_t)N*4, stream);
      k_dde_edge<<<CDIV(E,256),256,0,stream>>>(t_ids, h_ids, cur, nxt, E);
      k_dde_div<<<CDIV(N,256),256,0,stream>>>(nxt, degh, pe4, 2+r0, N);
      float* tmp=cur; cur=nxt; nxt=tmp;
    }
  }

  // ---- bounded BFS from anchor endpoints ----
  k_dist_init<<<CDIV(N,256),256,0,stream>>>(amask, dist, N);
  for (int it=0; it<3; it++){
    k_fill2<<<CDIV(N,256),256,0,stream>>>(c1, c2, 4, N);
    k_bfs_edge<<<CDIV(E,256),256,0,stream>>>(h_ids, t_ids, dist, c1, c2, E);
    k_bfs_comb<<<CDIV(N,256),256,0,stream>>>(dist, c1, c2, N);
  }

  // ---- encoder ----
  k_distW<<<5,256,0,stream>>>(dist_e, W_enc, distW);
  k_colvec<<<1,256,0,stream>>>(nontext, W_enc, nullptr, encnt);
  k_bgemm<256,false><<<CDIV(Ntext,32),256,0,stream>>>(ent, ent, BIGK1, pbWenc, B2, nullptr, nullptr, Ntext, 256);
  k_enc_fin<<<N,256,0,stream>>>(B2, encnt, b_enc, W_enc, pe4, dist, topic, amask, distW, B1, N, Ntext);

  // ---- 2-layer gated GNN ----
  for (int l=0;l<2;l++){
    const unsigned short* pT = l ? pbWmT1 : pbWmT0;
    const unsigned short* pB = l ? pbWmB1 : pbWmB0;
    const unsigned short* pG = l ? pbWg1  : pbWg0;
    const unsigned short* pU = l ? pbWu1  : pbWu0;
    float* hin  = l ? B2 : B1;
    float* hout = l ? B1 : B2;
    // mrel = rel @ Wm[256:512]
    k_bgemm<256,false><<<CDIV(R,32),256,0,stream>>>(rel, rel, BIGK1, pB, mrel, nullptr, nullptr, R, 256);
    // hm = h @ Wm[0:256]  -> B4
    k_bgemm<256,false><<<CDIV(N,32),256,0,stream>>>(hin, hin, BIGK1, pT, B4, nullptr, nullptr, N, 256);
    // agg = gather-sum relu(hm[h]+mrel[r]) over incoming edges of t  -> B3
    k_agg<<<N,256,0,stream>>>(offs, degi, eh, er, B4, mrel, B3, N);
    // gate_pre = [h,agg] @ Wg -> B4
    k_bgemm<256,false><<<CDIV(N,32),256,0,stream>>>(hin, B3, 256, pG, B4, nullptr, nullptr, N, 512);
    // hout = hin + sigmoid(gate_pre) * tanh(agg @ Wu)   (fused epilogue)
    k_bgemm<256,true><<<CDIV(N,32),256,0,stream>>>(B3, B3, BIGK1, pU, hout, hin, B4, N, 256);
  }

  // ---- output head: h_final = h @ W_out (h is in B1) ----
  k_bgemm<256,false><<<CDIV(N,32),256,0,stream>>>(B1, B1, BIGK1, pbWout, B2, nullptr, nullptr, N, 256);
  // UHT = h_final @ [W1_h | W1_t]  (N=512, written across B3|B4 which are contiguous)
  k_bgemm<512,false><<<CDIV(N,32),256,0,stream>>>(B2, B2, BIGK1, pbW1ht, B3, nullptr, nullptr, N, 256);
  // vrel = rel @ W1[512:768]
  k_bgemm<256,false><<<CDIV(R,32),256,0,stream>>>(rel, rel, BIGK1, pbW1r, vrel, nullptr, nullptr, R, 256);
  // bias2 = b1 + q @ W1[0:256]
  k_colvec<<<1,256,0,stream>>>(q, W1, b1, bias2);

  // ---- final scorer over all edges ----
  k_score<<<CDIV(E,4),256,0,stream>>>(h_ids, r_ids, t_ids, B3, vrel, bias2, topic,
                                      ai, as, W1+(size_t)1024*256, W2, b2, out, E);
}

// Round 4
// 679.487 us; speedup vs baseline: 3.7535x; 1.1279x over previous
//
#include <hip/hip_runtime.h>
#include <math.h>

#define CDIV(a,b) (((a)+(b)-1)/(b))

typedef short short8 __attribute__((ext_vector_type(8)));
typedef float f32x4  __attribute__((ext_vector_type(4)));
typedef unsigned short u16;

__device__ __forceinline__ float warp_sum(float v){
  #pragma unroll
  for (int o=32;o;o>>=1) v += __shfl_down(v,o);
  return v;
}
__device__ __forceinline__ u16 f2bf(float f){
  unsigned u = __float_as_uint(f);
  unsigned r = 0x7fffu + ((u>>16)&1u);
  return (u16)((u + r)>>16);
}
__device__ __forceinline__ float bl(u16 v){ return __uint_as_float(((unsigned)v)<<16); }

// ---------- fused row-dot (qe for entities, qr for relations) ----------
__global__ __launch_bounds__(256)
void k_rowdot_all(const float* __restrict__ ent, const float* __restrict__ nontext,
                  const float* __restrict__ q, float* __restrict__ qe,
                  int N, int Ntext,
                  const float* __restrict__ rel, float* __restrict__ qr, int R, int nb1){
  int wid = threadIdx.x>>6, lane = threadIdx.x&63;
  const float* src; float* dst; int row;
  if ((int)blockIdx.x < nb1){
    row = blockIdx.x*4 + wid; if (row >= N) return;
    src = (row < Ntext) ? (ent + (size_t)row*256) : nontext;
    dst = qe;
  } else {
    row = (blockIdx.x-nb1)*4 + wid; if (row >= R) return;
    src = rel + (size_t)row*256;
    dst = qr;
  }
  float4 a = *(const float4*)(src + lane*4);
  float4 b = *(const float4*)(q + lane*4);
  float s = a.x*b.x + a.y*b.y + a.z*b.z + a.w*b.w;
  s = warp_sum(s);
  if (!lane) dst[row] = s;
}

__global__ void k_tri(const int* __restrict__ h, const int* __restrict__ r,
                      const int* __restrict__ t, const float* __restrict__ qe,
                      const float* __restrict__ qr, float* __restrict__ tri, int E){
  int e = blockIdx.x*256 + threadIdx.x; if (e>=E) return;
  tri[e] = qe[h[e]] + qr[r[e]] + qe[t[e]];
}

// ---------- top-32 (exact, jax tie-break: lower index first) ----------
__global__ void k_bmax(const float* __restrict__ tri, float* __restrict__ bmax, int E){
  __shared__ float red[256];
  int chunk = CDIV(E, (int)gridDim.x);
  int lo = blockIdx.x*chunk, hi = min(E, lo+chunk);
  float m = -INFINITY;
  for (int i=lo+threadIdx.x; i<hi; i+=256) m = fmaxf(m, tri[i]);
  red[threadIdx.x]=m; __syncthreads();
  for (int s=128;s;s>>=1){ if ((int)threadIdx.x<s) red[threadIdx.x]=fmaxf(red[threadIdx.x],red[threadIdx.x+s]); __syncthreads(); }
  if (!threadIdx.x) bmax[blockIdx.x]=red[0];
}

__global__ void k_thresh(const float* __restrict__ bmax, float* __restrict__ thrT){
  __shared__ float v[256];
  __shared__ float red[256];
  __shared__ int who;
  int t = threadIdx.x;
  v[t] = bmax[t];
  __syncthreads();
  for (int it=0; it<32; it++){
    red[t]=v[t]; __syncthreads();
    for (int s=128;s;s>>=1){ if (t<s) red[t]=fmaxf(red[t],red[t+s]); __syncthreads(); }
    float m = red[0];
    if (it==31 && t==0) thrT[0]=m;
    if (t==0) who = 256;
    __syncthreads();
    if (v[t]==m) atomicMin(&who, t);
    __syncthreads();
    if (t==who) v[t] = -INFINITY;
    __syncthreads();
  }
}

__global__ void k_compact(const float* __restrict__ tri, const float* __restrict__ thrT,
                          int* __restrict__ cnt, int* __restrict__ ci, float* __restrict__ cv, int E){
  int e = blockIdx.x*256 + threadIdx.x; if (e>=E) return;
  float v = tri[e];
  if (v >= thrT[0]){
    int p = atomicAdd(cnt, 1);
    ci[p]=e; cv[p]=v;
  }
}

// final top-32 + topic/anchor mask fill (single block)
__global__ __launch_bounds__(256)
void k_final32(const int* __restrict__ ci, float* __restrict__ cv, const int* __restrict__ cnt,
               int* __restrict__ ai, float* __restrict__ as,
               const int* __restrict__ h_ids, const int* __restrict__ t_ids,
               const int* __restrict__ topicId, int nTopic,
               float* __restrict__ topic, float* __restrict__ amask){
  int C = *cnt;
  int t = threadIdx.x;
  __shared__ float rv[256]; __shared__ int ri[256]; __shared__ int rp[256];
  for (int it=0; it<32; it++){
    float bv=-INFINITY; int bi=0x7fffffff; int bp=-1;
    for (int p=t; p<C; p+=256){
      float v = cv[p]; int i = ci[p];
      if (v>bv || (v==bv && i<bi)){ bv=v; bi=i; bp=p; }
    }
    rv[t]=bv; ri[t]=bi; rp[t]=bp; __syncthreads();
    for (int s=128;s;s>>=1){
      if (t<s){
        if (rv[t+s]>rv[t] || (rv[t+s]==rv[t] && ri[t+s]<ri[t])){ rv[t]=rv[t+s]; ri[t]=ri[t+s]; rp[t]=rp[t+s]; }
      }
      __syncthreads();
    }
    if (t==0){ ai[it]=ri[0]; as[it]=rv[0]; cv[rp[0]] = -INFINITY; }
    __syncthreads();
  }
  // masks
  if (t < 32){
    int e = ai[t];
    amask[h_ids[e]] = 1.f;
    amask[t_ids[e]] = 1.f;
  }
  if (t < nTopic) topic[topicId[t]] = 1.f;
}

// ---------- degree histograms (int) ----------
__global__ void k_deghist(const int* __restrict__ h, const int* __restrict__ t,
                          int* __restrict__ degh, int* __restrict__ degi, int E){
  int e = blockIdx.x*256+threadIdx.x; if (e>=E) return;
  atomicAdd(&degh[h[e]], 1);
  atomicAdd(&degi[t[e]], 1);
}

// ---------- DDE ----------
__global__ void k_dde_edge(const int* __restrict__ src, const int* __restrict__ dst,
                           const float* __restrict__ s, float* __restrict__ sn, int E){
  int e = blockIdx.x*256+threadIdx.x; if (e>=E) return;
  atomicAdd(&sn[dst[e]], s[src[e]]);
}
__global__ void k_dde_div(float* __restrict__ sn, const int* __restrict__ deg,
                          float* __restrict__ pe4, int col, float* __restrict__ zbuf, int N){
  int i = blockIdx.x*256+threadIdx.x; if (i>=N) return;
  float v = sn[i] / fmaxf((float)deg[i], 1.f);
  sn[i] = v;
  pe4[i*4+col] = v;
  if (zbuf) zbuf[i] = 0.f;
}

// ---------- BFS ----------
__global__ void k_dist_init(const float* __restrict__ amask, int* __restrict__ dist,
                            int* __restrict__ c1, int* __restrict__ c2, int N){
  int i = blockIdx.x*256+threadIdx.x; if (i>=N) return;
  dist[i] = (amask[i] > 0.f) ? 0 : 4;
  c1[i]=4; c2[i]=4;
}
__global__ void k_bfs_edge(const int* __restrict__ h, const int* __restrict__ t,
                           const int* __restrict__ dist, int* __restrict__ c1, int* __restrict__ c2, int E){
  int e = blockIdx.x*256+threadIdx.x; if (e>=E) return;
  int hh=h[e], tt=t[e];
  atomicMin(&c1[tt], dist[hh]+1);
  atomicMin(&c2[hh], dist[tt]+1);
}
__global__ void k_bfs_comb(int* __restrict__ dist, int* __restrict__ c1, int* __restrict__ c2,
                           int refill, int N){
  int i = blockIdx.x*256+threadIdx.x; if (i>=N) return;
  dist[i] = min(dist[i], min(c1[i], c2[i]));
  if (refill){ c1[i]=4; c2[i]=4; }
}

// ---------- CSR build ----------
__global__ void k_scan1(const int* __restrict__ deg, int* __restrict__ offs,
                        int* __restrict__ bsum, int N){
  __shared__ int s[256];
  int i = blockIdx.x*256 + threadIdx.x;
  int v = (i<N) ? deg[i] : 0;
  s[threadIdx.x] = v; __syncthreads();
  #pragma unroll
  for (int o=1;o<256;o<<=1){
    int add = (threadIdx.x>=(unsigned)o) ? s[threadIdx.x-o] : 0; __syncthreads();
    s[threadIdx.x] += add; __syncthreads();
  }
  if (i<N) offs[i] = s[threadIdx.x] - v;
  if (threadIdx.x==255) bsum[blockIdx.x] = s[255];
}
__global__ void k_scan2(int* __restrict__ bsum, int nb){
  __shared__ int s[128];
  int t=threadIdx.x;
  int v = (t<nb)? bsum[t]:0;
  s[t]=v; __syncthreads();
  #pragma unroll
  for (int o=1;o<128;o<<=1){ int add=(t>=o)?s[t-o]:0; __syncthreads(); s[t]+=add; __syncthreads(); }
  if (t<nb) bsum[t] = s[t]-v;
}
__global__ void k_scan3(int* __restrict__ offs, const int* __restrict__ bsum,
                        int* __restrict__ cursor, int N){
  int i = blockIdx.x*256+threadIdx.x; if (i>=N) return;
  int o = offs[i] + bsum[blockIdx.x];
  offs[i]=o; cursor[i]=o;
}
__global__ void k_place(const int* __restrict__ h, const int* __restrict__ r,
                        const int* __restrict__ t, int* __restrict__ cursor,
                        int* __restrict__ eh, int* __restrict__ er, int E){
  int e = blockIdx.x*256+threadIdx.x; if (e>=E) return;
  int pos = atomicAdd(&cursor[t[e]], 1);
  eh[pos]=h[e]; er[pos]=r[e];
}

// ---------- fused small dense (distW rows 0-4, encnt, bias2) ----------
__global__ void k_smalls(const float* __restrict__ dist_e, const float* __restrict__ W_enc,
                         float* __restrict__ distW,
                         const float* __restrict__ nontext, float* __restrict__ encnt,
                         const float* __restrict__ q, const float* __restrict__ W1,
                         const float* __restrict__ b1, float* __restrict__ bias2){
  int b = blockIdx.x, j = threadIdx.x;
  if (b < 5){
    const float* Wpe = W_enc + (256+4)*256;
    float s=0.f;
    #pragma unroll
    for (int p=0;p<16;p++) s += dist_e[b*16+p]*Wpe[p*256+j];
    distW[b*256+j]=s;
  } else if (b == 5){
    float s=0.f;
    for (int k=0;k<256;k++) s += nontext[k]*W_enc[k*256+j];
    encnt[j]=s;
  } else {
    float s=b1[j];
    for (int k=0;k<256;k++) s += q[k]*W1[k*256+j];
    bias2[j]=s;
  }
}

// ---------- fused weight pack: all B operands -> bf16 MFMA frag order ----------
// frag f: lane l holds B[ks*32 + 8*(l>>4)+i][nt*16 + (l&15)], frag idx = ks*nt16+nt
__global__ __launch_bounds__(64)
void k_packall(const float* __restrict__ W_enc, const float* __restrict__ W_msg,
               const float* __restrict__ W_gate, const float* __restrict__ W_upd,
               const float* __restrict__ W_out, const float* __restrict__ W1,
               u16* __restrict__ pbAll){
  const int fragBase[11] = {0,128,256,384,640,896,1024,1152,1280,1536,1920};
  int f = blockIdx.x;
  int tgt = 0;
  #pragma unroll
  for (int i=1;i<10;i++) if (f >= fragBase[i]) tgt = i;
  int fid = f - fragBase[tgt];
  int nt16 = (tgt==8) ? 32 : (tgt==9 ? 48 : 16);
  int ks = fid / nt16, nt = fid % nt16;
  int lane = threadIdx.x;
  int k = ks*32 + 8*(lane>>4);
  int n = nt*16 + (lane&15);
  const float* src; int rowBase;
  switch (tgt){
    case 0: src=W_enc;  rowBase=0;   break;
    case 1: src=W_msg;  rowBase=0;   break;
    case 2: src=W_msg;  rowBase=512; break;
    case 3: src=W_gate; rowBase=0;   break;
    case 4: src=W_gate; rowBase=512; break;
    case 5: src=W_upd;  rowBase=0;   break;
    case 6: src=W_upd;  rowBase=256; break;
    case 7: src=W_out;  rowBase=0;   break;
    case 8: src=W1;     rowBase=(n<256)?256:768; break;
    default: src = (n<512)? W_msg : W1;
             rowBase = (n<256)?256 : (n<512?768:512); break;
  }
  int col = n & 255;
  u16 v[8];
  #pragma unroll
  for (int i=0;i<8;i++) v[i] = f2bf(src[(size_t)(rowBase+k+i)*256 + col]);
  u16* dst = pbAll + ((size_t)f*64 + lane)*8;
  *(uint4*)dst = *(uint4*)v;
}

// ---------- MFMA bf16 GEMM ----------
// A: k<K1 from A1 (fp32, stride 256); k>=K1 from A2 (bf16, stride 256).
// MODE: 0 fp32 out, 1 bf16 out, 2 gated (hin fp32 + sigmoid(gpre bf16)*tanh(acc)),
//       3 enc epilogue (PE adds + relu, fp32 out)
template<int NCOLS, int MODE>
__global__ __launch_bounds__(256)
void k_bgemm(const float* __restrict__ A1, const u16* __restrict__ A2, int K1,
             const u16* __restrict__ Bp, void* __restrict__ Cout,
             const float* __restrict__ hin, const u16* __restrict__ gpre,
             const float* __restrict__ b_enc, const float* __restrict__ W_enc,
             const float* __restrict__ pe4, const int* __restrict__ dist,
             const float* __restrict__ topic, const float* __restrict__ amask,
             const float* __restrict__ distW,
             int M, int K)
{
  constexpr int NT16 = NCOLS/16;
  constexpr int NREP = NCOLS/32;
  const int tid  = threadIdx.x;
  const int lane = tid & 63;
  const int w    = tid >> 6;
  const int wr   = w >> 1, wc = w & 1;
  const int row0 = blockIdx.x*32 + wr*16;
  const int lrow = lane & 15;
  const int kc   = lane >> 4;
  int arow = row0 + lrow;
  if (arow >= M) arow = M-1;

  f32x4 acc[NREP];
  #pragma unroll
  for (int n=0;n<NREP;n++) acc[n] = (f32x4){0.f,0.f,0.f,0.f};

  const int ksteps = K/32;
  for (int ks=0; ks<ksteps; ks++){
    int k0 = ks*32;
    short8 af;
    if (k0 < K1){
      const float* ap = A1 + (size_t)arow*256 + k0 + kc*8;
      float4 a0 = *(const float4*)ap;
      float4 a1 = *(const float4*)(ap+4);
      af[0]=(short)f2bf(a0.x); af[1]=(short)f2bf(a0.y); af[2]=(short)f2bf(a0.z); af[3]=(short)f2bf(a0.w);
      af[4]=(short)f2bf(a1.x); af[5]=(short)f2bf(a1.y); af[6]=(short)f2bf(a1.z); af[7]=(short)f2bf(a1.w);
    } else {
      const u16* ap = A2 + (size_t)arow*256 + (k0-K1) + kc*8;
      af = *(const short8*)ap;
    }
    const u16* bp = Bp + ((size_t)(ks*NT16 + wc*NREP)*64 + lane)*8;
    #pragma unroll
    for (int n=0;n<NREP;n++){
      short8 bf = *(const short8*)(bp + (size_t)n*64*8);
      acc[n] = __builtin_amdgcn_mfma_f32_16x16x32_bf16(af, bf, acc[n], 0, 0, 0);
    }
  }

  #pragma unroll
  for (int r=0;r<4;r++){
    int orow = row0 + 4*kc + r;
    if (orow >= M) continue;
    float p0,p1,p2,p3,tp,am; int dd=0;
    if (MODE==3){
      p0=pe4[orow*4+0]; p1=pe4[orow*4+1]; p2=pe4[orow*4+2]; p3=pe4[orow*4+3];
      dd=dist[orow]; tp=topic[orow]; am=amask[orow];
    }
    #pragma unroll
    for (int n=0;n<NREP;n++){
      int col = wc*(NCOLS/2) + n*16 + lrow;
      float v = acc[n][r];
      if (MODE==0){
        ((float*)Cout)[(size_t)orow*NCOLS + col] = v;
      } else if (MODE==1){
        ((u16*)Cout)[(size_t)orow*NCOLS + col] = f2bf(v);
      } else if (MODE==2){
        size_t idx = (size_t)orow*256 + col;
        float g = 1.f/(1.f+expf(-bl(gpre[idx])));
        ((float*)Cout)[idx] = hin[idx] + g * tanhf(v);
      } else {
        const float* Wpe = W_enc + 256*256;
        v += b_enc[col] + Wpe[22*256+col]
           + p0*Wpe[col] + p1*Wpe[256+col] + p2*Wpe[512+col] + p3*Wpe[768+col]
           + distW[dd*256+col] + tp*Wpe[20*256+col] + am*Wpe[21*256+col];
        ((float*)Cout)[(size_t)orow*256 + col] = fmaxf(v, 0.f);
      }
    }
  }
}

// ---------- non-text rows of encoder ----------
__global__ __launch_bounds__(256)
void k_encnt_fill(const float* __restrict__ encnt, const float* __restrict__ b_enc,
                  const float* __restrict__ W_enc, const float* __restrict__ pe4,
                  const int* __restrict__ dist, const float* __restrict__ topic,
                  const float* __restrict__ amask, const float* __restrict__ distW,
                  float* __restrict__ h, int Ntext){
  int i = Ntext + blockIdx.x, j = threadIdx.x;
  const float* Wpe = W_enc + 256*256;
  float p0=pe4[i*4+0], p1=pe4[i*4+1], p2=pe4[i*4+2], p3=pe4[i*4+3];
  int d = dist[i];
  float tp = topic[i], am = amask[i];
  float v = encnt[j] + b_enc[j] + Wpe[22*256+j]
          + p0*Wpe[j] + p1*Wpe[256+j] + p2*Wpe[512+j] + p3*Wpe[768+j]
          + distW[d*256+j] + tp*Wpe[20*256+j] + am*Wpe[21*256+j];
  h[(size_t)i*256+j] = fmaxf(v, 0.f);
}

// ---------- GNN aggregation: CSR gather over bf16 tables ----------
__global__ __launch_bounds__(256)
void k_agg(const int* __restrict__ offs, const int* __restrict__ degi,
           const int* __restrict__ eh, const int* __restrict__ er,
           const u16* __restrict__ hm, const u16* __restrict__ relC, int colOff,
           u16* __restrict__ agg, int N){
  int i = blockIdx.x; if (i>=N) return;
  int j = threadIdx.x;
  int start = offs[i], cnt = degi[i];
  float acc = 0.f;
  for (int k=0;k<cnt;k++){
    int h = eh[start+k], r = er[start+k];
    acc += fmaxf(bl(hm[(size_t)h*256+j]) + bl(relC[(size_t)r*768+colOff+j]), 0.f);
  }
  agg[(size_t)i*256+j] = f2bf(acc);
}

// ---------- scorer over all edges (bf16 tables) ----------
__global__ __launch_bounds__(256)
void k_score(const int* __restrict__ h_ids, const int* __restrict__ r_ids, const int* __restrict__ t_ids,
             const u16* __restrict__ UHT, const u16* __restrict__ relC,
             const float* __restrict__ bias2, const float* __restrict__ topic,
             const int* __restrict__ aidx, const float* __restrict__ asc,
             const float* __restrict__ W1s, const float* __restrict__ W2,
             const float* __restrict__ b2, float* __restrict__ out, int E){
  __shared__ int s_ai[32]; __shared__ float s_as[32];
  if (threadIdx.x < 32){ s_ai[threadIdx.x]=aidx[threadIdx.x]; s_as[threadIdx.x]=asc[threadIdx.x]; }
  __syncthreads();
  int wid = threadIdx.x>>6, lane = threadIdx.x&63;
  int e = blockIdx.x*4 + wid; if (e>=E) return;
  int h=h_ids[e], r=r_ids[e], t=t_ids[e];
  float isA=0.f, aS=0.f;
  #pragma unroll
  for (int k=0;k<32;k++){ if (s_ai[k]==e){ isA=1.f; aS=s_as[k]; } }
  float th=topic[h], tt=topic[t];
  int c = lane*4;
  float4 acc = *(const float4*)(bias2 + c);
  uint2 ua = *(const uint2*)(UHT + (size_t)h*512 + c);
  uint2 ud = *(const uint2*)(UHT + (size_t)t*512 + 256 + c);
  uint2 ub = *(const uint2*)(relC + (size_t)r*768 + 512 + c);
  acc.x += bl(ua.x&0xffff)+bl(ub.x&0xffff)+bl(ud.x&0xffff);
  acc.y += bl(ua.x>>16)  +bl(ub.x>>16)  +bl(ud.x>>16);
  acc.z += bl(ua.y&0xffff)+bl(ub.y&0xffff)+bl(ud.y&0xffff);
  acc.w += bl(ua.y>>16)  +bl(ub.y>>16)  +bl(ud.y>>16);
  float4 w0 = *(const float4*)(W1s + 0*256 + c);
  float4 w1 = *(const float4*)(W1s + 1*256 + c);
  float4 w2 = *(const float4*)(W1s + 2*256 + c);
  float4 w3 = *(const float4*)(W1s + 3*256 + c);
  acc.x += isA*w0.x + aS*w1.x + th*w2.x + tt*w3.x;
  acc.y += isA*w0.y + aS*w1.y + th*w2.y + tt*w3.y;
  acc.z += isA*w0.z + aS*w1.z + th*w2.z + tt*w3.z;
  acc.w += isA*w0.w + aS*w1.w + th*w2.w + tt*w3.w;
  acc.x=fmaxf(acc.x,0.f); acc.y=fmaxf(acc.y,0.f); acc.z=fmaxf(acc.z,0.f); acc.w=fmaxf(acc.w,0.f);
  float4 w = *(const float4*)(W2 + c);
  float p = acc.x*w.x + acc.y*w.y + acc.z*w.z + acc.w*w.w;
  p = warp_sum(p);
  if (!lane) out[e] = p + b2[0];
}

// ---------- host ----------
extern "C" void kernel_launch(void* const* d_in, const int* in_sizes, int n_in,
                              void* d_out, int out_size, void* d_ws, size_t ws_size,
                              hipStream_t stream)
{
  const int*   h_ids   = (const int*)d_in[0];
  const int*   r_ids   = (const int*)d_in[1];
  const int*   t_ids   = (const int*)d_in[2];
  const float* q       = (const float*)d_in[3];
  const float* ent     = (const float*)d_in[4];
  const float* rel     = (const float*)d_in[5];
  const int*   topicId = (const int*)d_in[6];
  const float* nontext = (const float*)d_in[9];
  const float* dist_e  = (const float*)d_in[10];
  const float* W_enc   = (const float*)d_in[11];
  const float* b_enc   = (const float*)d_in[12];
  const float* W_msg   = (const float*)d_in[13];
  const float* W_gate  = (const float*)d_in[14];
  const float* W_upd   = (const float*)d_in[15];
  const float* W_out   = (const float*)d_in[16];
  const float* W1      = (const float*)d_in[17];
  const float* b1      = (const float*)d_in[18];
  const float* W2      = (const float*)d_in[19];
  const float* b2      = (const float*)d_in[20];
  float* out = (float*)d_out;

  const int E = in_sizes[0];
  const int Ntext = in_sizes[4]/256;
  const int R = in_sizes[5]/256;
  const int NT = 500;
  const int N = Ntext + NT;
  const int nTopic = in_sizes[6];
  const int BIGK1 = 1<<28;

  char* ws = (char*)d_ws;
  size_t off = 0;
  auto alloc = [&](size_t bytes)->void*{
    size_t o = (off + 255) & ~(size_t)255;
    off = o + bytes;
    return (void*)(ws + o);
  };
  // big activations
  float* B1    = (float*)alloc((size_t)N*256*4);   // h ping ; later UHT alias
  float* B2    = (float*)alloc((size_t)N*256*4);   // h pong
  u16*   hmB   = (u16*)  alloc((size_t)N*256*2);   // hm ; later h_final
  u16*   aggB  = (u16*)  alloc((size_t)N*256*2);
  u16*   gpreB = (u16*)  alloc((size_t)N*256*2);
  u16*   relC  = (u16*)  alloc((size_t)R*768*2);   // [mrel0 | mrel1 | vrel]
  u16*   UHT   = (u16*)B1;                          // alias (h dead by then)
  u16*   hfB   = hmB;                               // alias (hm dead by then)
  // small
  float* qe    = (float*)alloc((size_t)N*4);
  float* qr    = (float*)alloc((size_t)R*4);
  float* tri   = (float*)alloc((size_t)E*4);
  float* bmax  = (float*)alloc(256*4);
  float* thrT  = (float*)alloc(4);
  int*   ci    = (int*)  alloc((size_t)E*4);
  float* cv    = (float*)alloc((size_t)E*4);
  int*   ai    = (int*)  alloc(32*4);
  float* as    = (float*)alloc(32*4);
  float* pe4   = (float*)alloc((size_t)N*16);
  int*   dist  = (int*)  alloc((size_t)N*4);
  int*   c1    = (int*)  alloc((size_t)N*4);
  int*   c2    = (int*)  alloc((size_t)N*4);
  float* distW = (float*)alloc(5*256*4);
  float* encnt = (float*)alloc(256*4);
  float* bias2 = (float*)alloc(256*4);
  int*   offs  = (int*)  alloc((size_t)N*4);
  int*   bsum  = (int*)  alloc(128*4);
  int*   cursor= (int*)  alloc((size_t)N*4);
  int*   eh    = (int*)  alloc((size_t)E*4);
  int*   er    = (int*)  alloc((size_t)E*4);
  u16*   pbAll = (u16*)  alloc((size_t)1920*512*2);
  // contiguous zero region
  int*   cnt   = (int*)  alloc(4);
  float* topic = (float*)alloc((size_t)N*4);
  float* amask = (float*)alloc((size_t)N*4);
  float* sA    = (float*)alloc((size_t)N*4);
  float* sB    = (float*)alloc((size_t)N*4);
  int*   deghI = (int*)  alloc((size_t)N*4);
  int*   degiI = (int*)  alloc((size_t)N*4);
  (void)ws_size; (void)n_in; (void)out_size;

  size_t zbytes = (char*)(degiI + N) - (char*)cnt;
  hipMemsetAsync(cnt, 0, zbytes, stream);

  // packed-weight offsets (ushort units = frag*512)
  u16* pbWenc = pbAll + (size_t)0*512;
  u16* pbWmT0 = pbAll + (size_t)128*512;
  u16* pbWmT1 = pbAll + (size_t)256*512;
  u16* pbWg0  = pbAll + (size_t)384*512;
  u16* pbWg1  = pbAll + (size_t)640*512;
  u16* pbWu0  = pbAll + (size_t)896*512;
  u16* pbWu1  = pbAll + (size_t)1024*512;
  u16* pbWout = pbAll + (size_t)1152*512;
  u16* pbW1ht = pbAll + (size_t)1280*512;
  u16* pbRelC = pbAll + (size_t)1536*512;

  k_packall<<<1920,64,0,stream>>>(W_enc, W_msg, W_gate, W_upd, W_out, W1, pbAll);

  // ---- triple scores + top-32 ----
  int nb1 = CDIV(N,4);
  k_rowdot_all<<<nb1+CDIV(R,4),256,0,stream>>>(ent, nontext, q, qe, N, Ntext, rel, qr, R, nb1);
  k_tri<<<CDIV(E,256),256,0,stream>>>(h_ids, r_ids, t_ids, qe, qr, tri, E);
  k_bmax<<<256,256,0,stream>>>(tri, bmax, E);
  k_thresh<<<1,256,0,stream>>>(bmax, thrT);
  k_compact<<<CDIV(E,256),256,0,stream>>>(tri, thrT, cnt, ci, cv, E);
  k_final32<<<1,256,0,stream>>>(ci, cv, cnt, ai, as, h_ids, t_ids, topicId, nTopic, topic, amask);

  // ---- degrees + CSR ----
  k_deghist<<<CDIV(E,256),256,0,stream>>>(h_ids, t_ids, deghI, degiI, E);
  {
    int nb = CDIV(N,256);
    k_scan1<<<nb,256,0,stream>>>(degiI, offs, bsum, N);
    k_scan2<<<1,128,0,stream>>>(bsum, nb);
    k_scan3<<<nb,256,0,stream>>>(offs, bsum, cursor, N);
    k_place<<<CDIV(E,256),256,0,stream>>>(h_ids, r_ids, t_ids, cursor, eh, er, E);
  }

  // ---- DDE (2 fwd + 2 rev); sA/sB pre-zeroed by memset; divs fold re-zeroing ----
  int nbN = CDIV(N,256);
  k_dde_edge<<<CDIV(E,256),256,0,stream>>>(h_ids, t_ids, topic, sB, E);
  k_dde_div <<<nbN,256,0,stream>>>(sB, degiI, pe4, 0, nullptr, N);
  k_dde_edge<<<CDIV(E,256),256,0,stream>>>(h_ids, t_ids, sB, sA, E);
  k_dde_div <<<nbN,256,0,stream>>>(sA, degiI, pe4, 1, sB, N);
  k_dde_edge<<<CDIV(E,256),256,0,stream>>>(t_ids, h_ids, topic, sB, E);
  k_dde_div <<<nbN,256,0,stream>>>(sB, deghI, pe4, 2, sA, N);
  k_dde_edge<<<CDIV(E,256),256,0,stream>>>(t_ids, h_ids, sB, sA, E);
  k_dde_div <<<nbN,256,0,stream>>>(sA, deghI, pe4, 3, nullptr, N);

  // ---- bounded BFS ----
  k_dist_init<<<nbN,256,0,stream>>>(amask, dist, c1, c2, N);
  for (int it=0; it<3; it++){
    k_bfs_edge<<<CDIV(E,256),256,0,stream>>>(h_ids, t_ids, dist, c1, c2, E);
    k_bfs_comb<<<nbN,256,0,stream>>>(dist, c1, c2, it<2, N);
  }

  // ---- small dense ----
  k_smalls<<<7,256,0,stream>>>(dist_e, W_enc, distW, nontext, encnt, q, W1, b1, bias2);

  // ---- relC = rel @ [WmB0 | WmB1 | W1r]  (bf16 out) ----
  k_bgemm<768,1><<<CDIV(R,32),256,0,stream>>>(rel, nullptr, BIGK1, pbRelC, relC,
      nullptr,nullptr,nullptr,nullptr,nullptr,nullptr,nullptr,nullptr,nullptr, R, 256);

  // ---- encoder (fused epilogue) ----
  k_bgemm<256,3><<<CDIV(Ntext,32),256,0,stream>>>(ent, nullptr, BIGK1, pbWenc, B1,
      nullptr,nullptr, b_enc, W_enc, pe4, dist, topic, amask, distW, Ntext, 256);
  k_encnt_fill<<<N-Ntext,256,0,stream>>>(encnt, b_enc, W_enc, pe4, dist, topic, amask, distW, B1, Ntext);

  // ---- 2-layer gated GNN ----
  for (int l=0;l<2;l++){
    const u16* pT = l ? pbWmT1 : pbWmT0;
    const u16* pG = l ? pbWg1  : pbWg0;
    const u16* pU = l ? pbWu1  : pbWu0;
    float* hin  = l ? B2 : B1;
    float* hout = l ? B1 : B2;
    // hm = h @ Wm_top  (bf16 out)
    k_bgemm<256,1><<<CDIV(N,32),256,0,stream>>>(hin, nullptr, BIGK1, pT, hmB,
        nullptr,nullptr,nullptr,nullptr,nullptr,nullptr,nullptr,nullptr,nullptr, N, 256);
    // agg = gather relu(hm[h]+mrel[r])
    k_agg<<<N,256,0,stream>>>(offs, degiI, eh, er, hmB, relC, l*256, aggB, N);
    // gate_pre = [h | agg] @ Wg  (bf16 out)
    k_bgemm<256,1><<<CDIV(N,32),256,0,stream>>>(hin, aggB, 256, pG, gpreB,
        nullptr,nullptr,nullptr,nullptr,nullptr,nullptr,nullptr,nullptr,nullptr, N, 512);
    // hout = hin + sigmoid(gpre)*tanh(agg @ Wu)
    k_bgemm<256,2><<<CDIV(N,32),256,0,stream>>>(nullptr, aggB, 0, pU, hout,
        hin, gpreB, nullptr,nullptr,nullptr,nullptr,nullptr,nullptr,nullptr, N, 256);
  }

  // ---- head ----
  // h_final = h @ W_out  (bf16, into hfB=hmB)
  k_bgemm<256,1><<<CDIV(N,32),256,0,stream>>>(B1, nullptr, BIGK1, pbWout, hfB,
      nullptr,nullptr,nullptr,nullptr,nullptr,nullptr,nullptr,nullptr,nullptr, N, 256);
  // UHT = h_final @ [W1_h | W1_t]  (bf16, into UHT=B1 alias)
  k_bgemm<512,1><<<CDIV(N,32),256,0,stream>>>(nullptr, hfB, 0, pbW1ht, UHT,
      nullptr,nullptr,nullptr,nullptr,nullptr,nullptr,nullptr,nullptr,nullptr, N, 256);

  // ---- final scorer ----
  k_score<<<CDIV(E,4),256,0,stream>>>(h_ids, r_ids, t_ids, UHT, relC, bias2, topic,
                                      ai, as, W1+(size_t)1024*256, W2, b2, out, E);
}

// Round 5
// 628.909 us; speedup vs baseline: 4.0554x; 1.0804x over previous
//
#include <hip/hip_runtime.h>
#include <math.h>

#define CDIV(a,b) (((a)+(b)-1)/(b))

typedef short short8 __attribute__((ext_vector_type(8)));
typedef float f32x4  __attribute__((ext_vector_type(4)));
typedef unsigned short u16;

__device__ __forceinline__ float warp_sum(float v){
  #pragma unroll
  for (int o=32;o;o>>=1) v += __shfl_down(v,o);
  return v;
}
__device__ __forceinline__ u16 f2bf(float f){
  unsigned u = __float_as_uint(f);
  unsigned r = 0x7fffu + ((u>>16)&1u);
  return (u16)((u + r)>>16);
}
__device__ __forceinline__ float bl(u16 v){ return __uint_as_float(((unsigned)v)<<16); }

// ---------- fused row-dot (qe for entities, qr for relations) ----------
__global__ __launch_bounds__(256)
void k_rowdot_all(const float* __restrict__ ent, const float* __restrict__ nontext,
                  const float* __restrict__ q, float* __restrict__ qe,
                  int N, int Ntext,
                  const float* __restrict__ rel, float* __restrict__ qr, int R, int nb1){
  int wid = threadIdx.x>>6, lane = threadIdx.x&63;
  const float* src; float* dst; int row;
  if ((int)blockIdx.x < nb1){
    row = blockIdx.x*4 + wid; if (row >= N) return;
    src = (row < Ntext) ? (ent + (size_t)row*256) : nontext;
    dst = qe;
  } else {
    row = (blockIdx.x-nb1)*4 + wid; if (row >= R) return;
    src = rel + (size_t)row*256;
    dst = qr;
  }
  float4 a = *(const float4*)(src + lane*4);
  float4 b = *(const float4*)(q + lane*4);
  float s = a.x*b.x + a.y*b.y + a.z*b.z + a.w*b.w;
  s = warp_sum(s);
  if (!lane) dst[row] = s;
}

// ---------- tri + per-block max + degree hist (fused) ----------
__global__ __launch_bounds__(256)
void k_tri(const int* __restrict__ h, const int* __restrict__ r,
           const int* __restrict__ t, const float* __restrict__ qe,
           const float* __restrict__ qr, float* __restrict__ tri,
           float* __restrict__ bmax, int* __restrict__ degh, int* __restrict__ degi, int E){
  __shared__ float red[256];
  int e = blockIdx.x*256 + threadIdx.x;
  float v = -INFINITY;
  if (e < E){
    int hh=h[e], rr=r[e], tt=t[e];
    v = qe[hh] + qr[rr] + qe[tt];
    tri[e] = v;
    atomicAdd(&degh[hh], 1);
    atomicAdd(&degi[tt], 1);
  }
  red[threadIdx.x]=v; __syncthreads();
  for (int s=128;s;s>>=1){ if ((int)threadIdx.x<s) red[threadIdx.x]=fmaxf(red[threadIdx.x],red[threadIdx.x+s]); __syncthreads(); }
  if (!threadIdx.x) bmax[blockIdx.x]=red[0];
}

__global__ void k_thresh(const float* __restrict__ bmax, float* __restrict__ thrT, int nb){
  __shared__ float v[256];
  __shared__ float red[256];
  __shared__ int who;
  int t = threadIdx.x;
  float m0 = -INFINITY;
  for (int i=t; i<nb; i+=256) m0 = fmaxf(m0, bmax[i]);
  v[t] = m0;
  __syncthreads();
  for (int it=0; it<32; it++){
    red[t]=v[t]; __syncthreads();
    for (int s=128;s;s>>=1){ if (t<s) red[t]=fmaxf(red[t],red[t+s]); __syncthreads(); }
    float m = red[0];
    if (it==31 && t==0) thrT[0]=m;
    if (t==0) who = 256;
    __syncthreads();
    if (v[t]==m) atomicMin(&who, t);
    __syncthreads();
    if (t==who) v[t] = -INFINITY;
    __syncthreads();
  }
}

__global__ void k_compact(const float* __restrict__ tri, const float* __restrict__ thrT,
                          int* __restrict__ cnt, int* __restrict__ ci, float* __restrict__ cv, int E){
  int e = blockIdx.x*256 + threadIdx.x; if (e>=E) return;
  float v = tri[e];
  if (v >= thrT[0]){
    int p = atomicAdd(cnt, 1);
    ci[p]=e; cv[p]=v;
  }
}

// final top-32 + topic/anchor mask fill (single block)
__global__ __launch_bounds__(256)
void k_final32(const int* __restrict__ ci, float* __restrict__ cv, const int* __restrict__ cnt,
               int* __restrict__ ai, float* __restrict__ as,
               const int* __restrict__ h_ids, const int* __restrict__ t_ids,
               const int* __restrict__ topicId, int nTopic,
               float* __restrict__ topic, float* __restrict__ amask){
  int C = *cnt;
  int t = threadIdx.x;
  __shared__ float rv[256]; __shared__ int ri[256]; __shared__ int rp[256];
  for (int it=0; it<32; it++){
    float bv=-INFINITY; int bi=0x7fffffff; int bp=-1;
    for (int p=t; p<C; p+=256){
      float v = cv[p]; int i = ci[p];
      if (v>bv || (v==bv && i<bi)){ bv=v; bi=i; bp=p; }
    }
    rv[t]=bv; ri[t]=bi; rp[t]=bp; __syncthreads();
    for (int s=128;s;s>>=1){
      if (t<s){
        if (rv[t+s]>rv[t] || (rv[t+s]==rv[t] && ri[t+s]<ri[t])){ rv[t]=rv[t+s]; ri[t]=ri[t+s]; rp[t]=rp[t+s]; }
      }
      __syncthreads();
    }
    if (t==0){ ai[it]=ri[0]; as[it]=rv[0]; cv[rp[0]] = -INFINITY; }
    __syncthreads();
  }
  if (t < 32){
    int e = ai[t];
    amask[h_ids[e]] = 1.f;
    amask[t_ids[e]] = 1.f;
  }
  if (t < nTopic) topic[topicId[t]] = 1.f;
}

// ---------- DDE ----------
__global__ void k_dde_edge(const int* __restrict__ src, const int* __restrict__ dst,
                           const float* __restrict__ s, float* __restrict__ sn, int E){
  int e = blockIdx.x*256+threadIdx.x; if (e>=E) return;
  atomicAdd(&sn[dst[e]], s[src[e]]);
}
// div + re-zero another buffer + (optional) BFS dist/c init fold
__global__ void k_dde_div(float* __restrict__ sn, const int* __restrict__ deg,
                          float* __restrict__ pe4, int col, float* __restrict__ zbuf,
                          const float* __restrict__ amask, int* __restrict__ dist,
                          int* __restrict__ cc, int N){
  int i = blockIdx.x*256+threadIdx.x; if (i>=N) return;
  float v = sn[i] / fmaxf((float)deg[i], 1.f);
  sn[i] = v;
  pe4[i*4+col] = v;
  if (zbuf) zbuf[i] = 0.f;
  if (dist){
    dist[i] = (amask[i] > 0.f) ? 0 : 4;
    cc[i] = 4;
  }
}

// ---------- BFS (single candidate array) ----------
__global__ void k_bfs_edge(const int* __restrict__ h, const int* __restrict__ t,
                           const int* __restrict__ dist, int* __restrict__ cc, int E){
  int e = blockIdx.x*256+threadIdx.x; if (e>=E) return;
  int hh=h[e], tt=t[e];
  atomicMin(&cc[tt], dist[hh]+1);
  atomicMin(&cc[hh], dist[tt]+1);
}
__global__ void k_bfs_comb(int* __restrict__ dist, int* __restrict__ cc, int refill, int N){
  int i = blockIdx.x*256+threadIdx.x; if (i>=N) return;
  dist[i] = min(dist[i], cc[i]);
  if (refill) cc[i]=4;
}

// ---------- CSR build ----------
__global__ void k_scan1(const int* __restrict__ deg, int* __restrict__ offs,
                        int* __restrict__ bsum, int N){
  __shared__ int s[256];
  int i = blockIdx.x*256 + threadIdx.x;
  int v = (i<N) ? deg[i] : 0;
  s[threadIdx.x] = v; __syncthreads();
  #pragma unroll
  for (int o=1;o<256;o<<=1){
    int add = (threadIdx.x>=(unsigned)o) ? s[threadIdx.x-o] : 0; __syncthreads();
    s[threadIdx.x] += add; __syncthreads();
  }
  if (i<N) offs[i] = s[threadIdx.x] - v;
  if (threadIdx.x==255) bsum[blockIdx.x] = s[255];
}
__global__ void k_scan2(int* __restrict__ bsum, int nb){
  __shared__ int s[128];
  int t=threadIdx.x;
  int v = (t<nb)? bsum[t]:0;
  s[t]=v; __syncthreads();
  #pragma unroll
  for (int o=1;o<128;o<<=1){ int add=(t>=o)?s[t-o]:0; __syncthreads(); s[t]+=add; __syncthreads(); }
  if (t<nb) bsum[t] = s[t]-v;
}
__global__ void k_scan3(int* __restrict__ offs, const int* __restrict__ bsum,
                        int* __restrict__ cursor, int N){
  int i = blockIdx.x*256+threadIdx.x; if (i>=N) return;
  int o = offs[i] + bsum[blockIdx.x];
  offs[i]=o; cursor[i]=o;
}
__global__ void k_place(const int* __restrict__ h, const int* __restrict__ r,
                        const int* __restrict__ t, int* __restrict__ cursor,
                        int2* __restrict__ ehr, int E){
  int e = blockIdx.x*256+threadIdx.x; if (e>=E) return;
  int pos = atomicAdd(&cursor[t[e]], 1);
  ehr[pos] = make_int2(h[e], r[e]);
}

// ---------- fused small dense (distW rows 0-4, encnt, bias2) ----------
__global__ void k_smalls(const float* __restrict__ dist_e, const float* __restrict__ W_enc,
                         float* __restrict__ distW,
                         const float* __restrict__ nontext, float* __restrict__ encnt,
                         const float* __restrict__ q, const float* __restrict__ W1,
                         const float* __restrict__ b1, float* __restrict__ bias2){
  int b = blockIdx.x, j = threadIdx.x;
  if (b < 5){
    const float* Wpe = W_enc + (256+4)*256;
    float s=0.f;
    #pragma unroll
    for (int p=0;p<16;p++) s += dist_e[b*16+p]*Wpe[p*256+j];
    distW[b*256+j]=s;
  } else if (b == 5){
    float s=0.f;
    for (int k=0;k<256;k++) s += nontext[k]*W_enc[k*256+j];
    encnt[j]=s;
  } else {
    float s=b1[j];
    for (int k=0;k<256;k++) s += q[k]*W1[k*256+j];
    bias2[j]=s;
  }
}

// ---------- fused weight pack -> bf16 MFMA frag order ----------
// layout: [0,128) Wenc | [128,256) WmT0 | [256,384) WmT1 | [384,896) GU0 |
//         [896,1408) GU1 | [1408,1792) RelC | [1792,2048) W1ht
// GU: K=512, N=512 packed: blk even -> gate col, blk odd -> upd col (rows<256 zero)
__global__ __launch_bounds__(64)
void k_packall(const float* __restrict__ W_enc, const float* __restrict__ W_msg,
               const float* __restrict__ W_gate, const float* __restrict__ W_upd,
               const float* __restrict__ W1, u16* __restrict__ pbAll){
  int f = blockIdx.x, lane = threadIdx.x;
  int tgt, fid, nt16;
  if      (f < 128) { tgt=0; fid=f;      nt16=16; }
  else if (f < 256) { tgt=1; fid=f-128;  nt16=16; }
  else if (f < 384) { tgt=2; fid=f-256;  nt16=16; }
  else if (f < 896) { tgt=3; fid=f-384;  nt16=32; }
  else if (f < 1408){ tgt=4; fid=f-896;  nt16=32; }
  else if (f < 1792){ tgt=5; fid=f-1408; nt16=48; }
  else              { tgt=6; fid=f-1792; nt16=32; }
  int ks = fid/nt16, nt = fid%nt16;
  int kb = ks*32 + 8*(lane>>4);
  int n  = nt*16 + (lane&15);
  u16 v[8];
  #pragma unroll
  for (int i=0;i<8;i++){
    int k = kb+i;
    float x;
    if (tgt==0) x = W_enc[(size_t)k*256+n];
    else if (tgt==1) x = W_msg[(size_t)k*256+n];
    else if (tgt==2) x = W_msg[(size_t)(512+k)*256+n];
    else if (tgt==3 || tgt==4){
      const float* Wg = W_gate + (tgt==4 ? (size_t)512*256 : 0);
      const float* Wu = W_upd  + (tgt==4 ? (size_t)256*256 : 0);
      int blk = n>>4, c = ((blk>>1)<<4) | (n&15);
      if ((blk&1)==0) x = Wg[(size_t)k*256+c];
      else            x = (k<256) ? 0.f : Wu[(size_t)(k-256)*256+c];
    }
    else if (tgt==5){
      if (n<256)      x = W_msg[(size_t)(256+k)*256+n];
      else if (n<512) x = W_msg[(size_t)(768+k)*256+(n-256)];
      else            x = W1[(size_t)(512+k)*256+(n-512)];
    } else {
      if (n<256) x = W1[(size_t)(256+k)*256+n];
      else       x = W1[(size_t)(768+k)*256+(n-256)];
    }
    v[i]=f2bf(x);
  }
  *(uint4*)(pbAll + ((size_t)f*64+lane)*8) = *(uint4*)v;
}

// pack fp32 [256][512] -> 256 frags
__global__ __launch_bounds__(64)
void k_packf32(const float* __restrict__ W, u16* __restrict__ Bp){
  int f = blockIdx.x, lane = threadIdx.x;
  int ks = f/32, nt = f%32;
  int kb = ks*32 + 8*(lane>>4);
  int n  = nt*16 + (lane&15);
  u16 v[8];
  #pragma unroll
  for (int i=0;i<8;i++) v[i] = f2bf(W[(size_t)(kb+i)*512 + n]);
  *(uint4*)(Bp + ((size_t)f*64+lane)*8) = *(uint4*)v;
}

// ---------- MFMA bf16 GEMM ----------
// A: k<K1 from A1 (fp32, stride 256); k>=K1 from A2 (bf16, stride 256).
// MODE 0: fp32 out stride NCOLS.  MODE 1: bf16 out stride NCOLS.
// MODE 3: encoder epilogue (PE adds + relu) -> fp32 Cout stride 256 + bf16 hB.
// MODE 4: merged gate/upd: acc pairs (gate,upd) -> hout = hin + sig(g)*tanh(u),
//         fp32 Cout stride 256 + bf16 hB.
template<int NCOLS, int MODE>
__global__ __launch_bounds__(256)
void k_bgemm(const float* __restrict__ A1, const u16* __restrict__ A2, int K1,
             const u16* __restrict__ Bp, void* __restrict__ Cout,
             u16* __restrict__ hB, const float* __restrict__ hinF,
             const float* __restrict__ b_enc, const float* __restrict__ W_enc,
             const float* __restrict__ pe4, const int* __restrict__ dist,
             const float* __restrict__ topic, const float* __restrict__ amask,
             const float* __restrict__ distW,
             int M, int K)
{
  constexpr int NT16 = NCOLS/16;
  constexpr int NREP = NCOLS/32;
  const int tid  = threadIdx.x;
  const int lane = tid & 63;
  const int w    = tid >> 6;
  const int wr   = w >> 1, wc = w & 1;
  const int row0 = blockIdx.x*32 + wr*16;
  const int lrow = lane & 15;
  const int kc   = lane >> 4;
  int arow = row0 + lrow;
  if (arow >= M) arow = M-1;

  f32x4 acc[NREP];
  #pragma unroll
  for (int n=0;n<NREP;n++) acc[n] = (f32x4){0.f,0.f,0.f,0.f};

  const int ksteps = K/32;
  for (int ks=0; ks<ksteps; ks++){
    int k0 = ks*32;
    short8 af;
    if (k0 < K1){
      const float* ap = A1 + (size_t)arow*256 + k0 + kc*8;
      float4 a0 = *(const float4*)ap;
      float4 a1 = *(const float4*)(ap+4);
      af[0]=(short)f2bf(a0.x); af[1]=(short)f2bf(a0.y); af[2]=(short)f2bf(a0.z); af[3]=(short)f2bf(a0.w);
      af[4]=(short)f2bf(a1.x); af[5]=(short)f2bf(a1.y); af[6]=(short)f2bf(a1.z); af[7]=(short)f2bf(a1.w);
    } else {
      const u16* ap = A2 + (size_t)arow*256 + (k0-K1) + kc*8;
      af = *(const short8*)ap;
    }
    const u16* bp = Bp + ((size_t)(ks*NT16 + wc*NREP)*64 + lane)*8;
    #pragma unroll
    for (int n=0;n<NREP;n++){
      short8 bf = *(const short8*)(bp + (size_t)n*64*8);
      acc[n] = __builtin_amdgcn_mfma_f32_16x16x32_bf16(af, bf, acc[n], 0, 0, 0);
    }
  }

  #pragma unroll
  for (int r=0;r<4;r++){
    int orow = row0 + 4*kc + r;
    if (orow >= M) continue;
    if (MODE==0 || MODE==1){
      #pragma unroll
      for (int n=0;n<NREP;n++){
        int col = wc*(NCOLS/2) + n*16 + lrow;
        float v = acc[n][r];
        if (MODE==0) ((float*)Cout)[(size_t)orow*NCOLS + col] = v;
        else         ((u16*)Cout)[(size_t)orow*NCOLS + col] = f2bf(v);
      }
    } else if (MODE==3){
      float p0=pe4[orow*4+0], p1=pe4[orow*4+1], p2=pe4[orow*4+2], p3=pe4[orow*4+3];
      int dd=dist[orow];
      float tp=topic[orow], am=amask[orow];
      const float* Wpe = W_enc + 256*256;
      #pragma unroll
      for (int n=0;n<NREP;n++){
        int col = wc*(NCOLS/2) + n*16 + lrow;
        float v = acc[n][r];
        v += b_enc[col] + Wpe[22*256+col]
           + p0*Wpe[col] + p1*Wpe[256+col] + p2*Wpe[512+col] + p3*Wpe[768+col]
           + distW[dd*256+col] + tp*Wpe[20*256+col] + am*Wpe[21*256+col];
        v = fmaxf(v, 0.f);
        size_t idx = (size_t)orow*256 + col;
        ((float*)Cout)[idx] = v;
        hB[idx] = f2bf(v);
      }
    } else { // MODE 4
      #pragma unroll
      for (int k=0;k<NREP/2;k++){
        int col = wc*128 + k*16 + lrow;
        size_t idx = (size_t)orow*256 + col;
        float g = 1.f/(1.f+expf(-acc[2*k][r]));
        float u = tanhf(acc[2*k+1][r]);
        float v = hinF[idx] + g*u;
        ((float*)Cout)[idx] = v;
        hB[idx] = f2bf(v);
      }
    }
  }
}

// ---------- non-text rows of encoder ----------
__global__ __launch_bounds__(256)
void k_encnt_fill(const float* __restrict__ encnt, const float* __restrict__ b_enc,
                  const float* __restrict__ W_enc, const float* __restrict__ pe4,
                  const int* __restrict__ dist, const float* __restrict__ topic,
                  const float* __restrict__ amask, const float* __restrict__ distW,
                  float* __restrict__ h, u16* __restrict__ hB, int Ntext){
  int i = Ntext + blockIdx.x, j = threadIdx.x;
  const float* Wpe = W_enc + 256*256;
  float p0=pe4[i*4+0], p1=pe4[i*4+1], p2=pe4[i*4+2], p3=pe4[i*4+3];
  int d = dist[i];
  float tp = topic[i], am = amask[i];
  float v = encnt[j] + b_enc[j] + Wpe[22*256+j]
          + p0*Wpe[j] + p1*Wpe[256+j] + p2*Wpe[512+j] + p3*Wpe[768+j]
          + distW[d*256+j] + tp*Wpe[20*256+j] + am*Wpe[21*256+j];
  v = fmaxf(v, 0.f);
  h[(size_t)i*256+j] = v;
  hB[(size_t)i*256+j] = f2bf(v);
}

// ---------- GNN aggregation: wave per node, 4 cols/lane ----------
__global__ __launch_bounds__(256)
void k_agg(const int* __restrict__ offs, const int* __restrict__ degi,
           const int2* __restrict__ ehr,
           const u16* __restrict__ hm, const u16* __restrict__ relC, int colOff,
           u16* __restrict__ agg, int N){
  int wid = threadIdx.x>>6, lane = threadIdx.x&63;
  int i = blockIdx.x*4 + wid; if (i>=N) return;
  int start = offs[i], cnt = degi[i];
  int c4 = lane*4;
  float a0=0.f,a1=0.f,a2=0.f,a3=0.f;
  for (int k=0;k<cnt;k++){
    int2 hr = ehr[start+k];
    uint2 ua = *(const uint2*)(hm + (size_t)hr.x*256 + c4);
    uint2 ub = *(const uint2*)(relC + (size_t)hr.y*768 + colOff + c4);
    a0 += fmaxf(bl((u16)(ua.x&0xffff))+bl((u16)(ub.x&0xffff)),0.f);
    a1 += fmaxf(bl((u16)(ua.x>>16))  +bl((u16)(ub.x>>16)),  0.f);
    a2 += fmaxf(bl((u16)(ua.y&0xffff))+bl((u16)(ub.y&0xffff)),0.f);
    a3 += fmaxf(bl((u16)(ua.y>>16))  +bl((u16)(ub.y>>16)),  0.f);
  }
  uint2 o;
  o.x = (unsigned)f2bf(a0) | ((unsigned)f2bf(a1)<<16);
  o.y = (unsigned)f2bf(a2) | ((unsigned)f2bf(a3)<<16);
  *(uint2*)(agg + (size_t)i*256 + c4) = o;
}

// ---------- scorer math (shared by bulk + patch) ----------
__device__ __forceinline__ float edge_score(int lane, int h, int r, int t,
    const u16* __restrict__ UHT, const u16* __restrict__ relC,
    const float* __restrict__ bias2, const float* __restrict__ topic,
    const float* __restrict__ W1s, const float* __restrict__ W2,
    float isA, float aS){
  int c = lane*4;
  float4 acc = *(const float4*)(bias2 + c);
  uint2 ua = *(const uint2*)(UHT + (size_t)h*512 + c);
  uint2 ud = *(const uint2*)(UHT + (size_t)t*512 + 256 + c);
  uint2 ub = *(const uint2*)(relC + (size_t)r*768 + 512 + c);
  acc.x += bl((u16)(ua.x&0xffff))+bl((u16)(ub.x&0xffff))+bl((u16)(ud.x&0xffff));
  acc.y += bl((u16)(ua.x>>16))  +bl((u16)(ub.x>>16))  +bl((u16)(ud.x>>16));
  acc.z += bl((u16)(ua.y&0xffff))+bl((u16)(ub.y&0xffff))+bl((u16)(ud.y&0xffff));
  acc.w += bl((u16)(ua.y>>16))  +bl((u16)(ub.y>>16))  +bl((u16)(ud.y>>16));
  float th = topic[h], tt = topic[t];
  if (th!=0.f || tt!=0.f){
    float4 w2v = *(const float4*)(W1s + 2*256 + c);
    float4 w3v = *(const float4*)(W1s + 3*256 + c);
    acc.x += th*w2v.x + tt*w3v.x;
    acc.y += th*w2v.y + tt*w3v.y;
    acc.z += th*w2v.z + tt*w3v.z;
    acc.w += th*w2v.w + tt*w3v.w;
  }
  if (isA != 0.f){
    float4 w0 = *(const float4*)(W1s + 0*256 + c);
    float4 w1 = *(const float4*)(W1s + 1*256 + c);
    acc.x += isA*w0.x + aS*w1.x;
    acc.y += isA*w0.y + aS*w1.y;
    acc.z += isA*w0.z + aS*w1.z;
    acc.w += isA*w0.w + aS*w1.w;
  }
  acc.x=fmaxf(acc.x,0.f); acc.y=fmaxf(acc.y,0.f); acc.z=fmaxf(acc.z,0.f); acc.w=fmaxf(acc.w,0.f);
  float4 w = *(const float4*)(W2 + c);
  float p = acc.x*w.x + acc.y*w.y + acc.z*w.z + acc.w*w.w;
  return warp_sum(p);
}

__global__ __launch_bounds__(256)
void k_score(const int* __restrict__ h_ids, const int* __restrict__ r_ids, const int* __restrict__ t_ids,
             const u16* __restrict__ UHT, const u16* __restrict__ relC,
             const float* __restrict__ bias2, const float* __restrict__ topic,
             const float* __restrict__ W1s, const float* __restrict__ W2,
             const float* __restrict__ b2, float* __restrict__ out, int E){
  int wid = threadIdx.x>>6, lane = threadIdx.x&63;
  int e = blockIdx.x*4 + wid; if (e>=E) return;
  float p = edge_score(lane, h_ids[e], r_ids[e], t_ids[e], UHT, relC, bias2, topic, W1s, W2, 0.f, 0.f);
  if (!lane) out[e] = p + b2[0];
}

__global__ __launch_bounds__(256)
void k_patch(const int* __restrict__ ai, const float* __restrict__ as,
             const int* __restrict__ h_ids, const int* __restrict__ r_ids, const int* __restrict__ t_ids,
             const u16* __restrict__ UHT, const u16* __restrict__ relC,
             const float* __restrict__ bias2, const float* __restrict__ topic,
             const float* __restrict__ W1s, const float* __restrict__ W2,
             const float* __restrict__ b2, float* __restrict__ out){
  int wid = threadIdx.x>>6, lane = threadIdx.x&63;
  int k = blockIdx.x*4 + wid; if (k>=32) return;
  int e = ai[k];
  float p = edge_score(lane, h_ids[e], r_ids[e], t_ids[e], UHT, relC, bias2, topic, W1s, W2, 1.f, as[k]);
  if (!lane) out[e] = p + b2[0];
}

// ---------- host ----------
extern "C" void kernel_launch(void* const* d_in, const int* in_sizes, int n_in,
                              void* d_out, int out_size, void* d_ws, size_t ws_size,
                              hipStream_t stream)
{
  const int*   h_ids   = (const int*)d_in[0];
  const int*   r_ids   = (const int*)d_in[1];
  const int*   t_ids   = (const int*)d_in[2];
  const float* q       = (const float*)d_in[3];
  const float* ent     = (const float*)d_in[4];
  const float* rel     = (const float*)d_in[5];
  const int*   topicId = (const int*)d_in[6];
  const float* nontext = (const float*)d_in[9];
  const float* dist_e  = (const float*)d_in[10];
  const float* W_enc   = (const float*)d_in[11];
  const float* b_enc   = (const float*)d_in[12];
  const float* W_msg   = (const float*)d_in[13];
  const float* W_gate  = (const float*)d_in[14];
  const float* W_upd   = (const float*)d_in[15];
  const float* W_out   = (const float*)d_in[16];
  const float* W1      = (const float*)d_in[17];
  const float* b1      = (const float*)d_in[18];
  const float* W2      = (const float*)d_in[19];
  const float* b2      = (const float*)d_in[20];
  float* out = (float*)d_out;

  const int E = in_sizes[0];
  const int Ntext = in_sizes[4]/256;
  const int R = in_sizes[5]/256;
  const int NT = 500;
  const int N = Ntext + NT;
  const int nTopic = in_sizes[6];
  const int BIGK1 = 1<<28;

  char* ws = (char*)d_ws;
  size_t off = 0;
  auto alloc = [&](size_t bytes)->void*{
    size_t o = (off + 255) & ~(size_t)255;
    off = o + bytes;
    return (void*)(ws + o);
  };
  // big activations
  float* B1    = (float*)alloc((size_t)N*256*4);   // h fp32 ping
  float* B2    = (float*)alloc((size_t)N*256*4);   // h fp32 pong ; later UHT (u16 N*512)
  u16*   hB1   = (u16*)  alloc((size_t)N*256*2);   // h bf16 ping
  u16*   hB2   = (u16*)  alloc((size_t)N*256*2);   // h bf16 pong
  u16*   hmB   = (u16*)  alloc((size_t)N*256*2);
  u16*   aggB  = (u16*)  alloc((size_t)N*256*2);
  u16*   relC  = (u16*)  alloc((size_t)R*768*2);   // [mrel0 | mrel1 | vrel]
  float* WcombF= (float*)alloc((size_t)256*512*4); // W_out @ [W1h|W1t], fp32
  u16*   pbWcomb=(u16*)  alloc((size_t)256*512*2);
  u16*   UHT   = (u16*)B2;
  // small
  float* qe    = (float*)alloc((size_t)N*4);
  float* qr    = (float*)alloc((size_t)R*4);
  float* tri   = (float*)alloc((size_t)E*4);
  float* bmax  = (float*)alloc(1024*4);
  float* thrT  = (float*)alloc(4);
  int*   ci    = (int*)  alloc((size_t)E*4);
  float* cv    = (float*)alloc((size_t)E*4);
  int*   ai    = (int*)  alloc(32*4);
  float* as    = (float*)alloc(32*4);
  float* pe4   = (float*)alloc((size_t)N*16);
  int*   dist  = (int*)  alloc((size_t)N*4);
  int*   cbfs  = (int*)  alloc((size_t)N*4);
  float* distW = (float*)alloc(5*256*4);
  float* encnt = (float*)alloc(256*4);
  float* bias2 = (float*)alloc(256*4);
  int*   offs  = (int*)  alloc((size_t)N*4);
  int*   bsum  = (int*)  alloc(128*4);
  int*   cursor= (int*)  alloc((size_t)N*4);
  int2*  ehr   = (int2*) alloc((size_t)E*8);
  u16*   pbAll = (u16*)  alloc((size_t)2048*512*2);
  // contiguous zero region
  int*   cnt   = (int*)  alloc(4);
  float* topic = (float*)alloc((size_t)N*4);
  float* amask = (float*)alloc((size_t)N*4);
  float* sA    = (float*)alloc((size_t)N*4);
  float* sB    = (float*)alloc((size_t)N*4);
  int*   deghI = (int*)  alloc((size_t)N*4);
  int*   degiI = (int*)  alloc((size_t)N*4);
  (void)ws_size; (void)n_in; (void)out_size;

  size_t zbytes = (char*)(degiI + N) - (char*)cnt;
  hipMemsetAsync(cnt, 0, zbytes, stream);

  // packed-weight offsets (u16 units = frag*512)
  u16* pbWenc = pbAll + (size_t)0*512;
  u16* pbWmT0 = pbAll + (size_t)128*512;
  u16* pbWmT1 = pbAll + (size_t)256*512;
  u16* pbGU0  = pbAll + (size_t)384*512;
  u16* pbGU1  = pbAll + (size_t)896*512;
  u16* pbRelC = pbAll + (size_t)1408*512;
  u16* pbW1ht = pbAll + (size_t)1792*512;

  // ---- weights: pack, Wcomb = W_out @ [W1h|W1t], pack Wcomb ----
  k_packall<<<2048,64,0,stream>>>(W_enc, W_msg, W_gate, W_upd, W1, pbAll);
  k_bgemm<512,0><<<8,256,0,stream>>>(W_out, nullptr, BIGK1, pbW1ht, WcombF,
      nullptr,nullptr,nullptr,nullptr,nullptr,nullptr,nullptr,nullptr,nullptr, 256, 256);
  k_packf32<<<256,64,0,stream>>>(WcombF, pbWcomb);

  // ---- triple scores + top-32 (tri fused with blockmax + degree hist) ----
  int nb1 = CDIV(N,4);
  k_rowdot_all<<<nb1+CDIV(R,4),256,0,stream>>>(ent, nontext, q, qe, N, Ntext, rel, qr, R, nb1);
  int nbE = CDIV(E,256);
  k_tri<<<nbE,256,0,stream>>>(h_ids, r_ids, t_ids, qe, qr, tri, bmax, deghI, degiI, E);
  k_thresh<<<1,256,0,stream>>>(bmax, thrT, nbE);
  k_compact<<<nbE,256,0,stream>>>(tri, thrT, cnt, ci, cv, E);
  k_final32<<<1,256,0,stream>>>(ci, cv, cnt, ai, as, h_ids, t_ids, topicId, nTopic, topic, amask);

  // ---- CSR (by destination t) ----
  {
    int nb = CDIV(N,256);
    k_scan1<<<nb,256,0,stream>>>(degiI, offs, bsum, N);
    k_scan2<<<1,128,0,stream>>>(bsum, nb);
    k_scan3<<<nb,256,0,stream>>>(offs, bsum, cursor, N);
    k_place<<<nbE,256,0,stream>>>(h_ids, r_ids, t_ids, cursor, ehr, E);
  }

  // ---- DDE (2 fwd + 2 rev); last div folds BFS dist/c init ----
  int nbN = CDIV(N,256);
  k_dde_edge<<<nbE,256,0,stream>>>(h_ids, t_ids, topic, sB, E);
  k_dde_div <<<nbN,256,0,stream>>>(sB, degiI, pe4, 0, nullptr, nullptr,nullptr,nullptr, N);
  k_dde_edge<<<nbE,256,0,stream>>>(h_ids, t_ids, sB, sA, E);
  k_dde_div <<<nbN,256,0,stream>>>(sA, degiI, pe4, 1, sB, nullptr,nullptr,nullptr, N);
  k_dde_edge<<<nbE,256,0,stream>>>(t_ids, h_ids, topic, sB, E);
  k_dde_div <<<nbN,256,0,stream>>>(sB, deghI, pe4, 2, sA, nullptr,nullptr,nullptr, N);
  k_dde_edge<<<nbE,256,0,stream>>>(t_ids, h_ids, sB, sA, E);
  k_dde_div <<<nbN,256,0,stream>>>(sA, deghI, pe4, 3, nullptr, amask, dist, cbfs, N);

  // ---- bounded BFS ----
  for (int it=0; it<3; it++){
    k_bfs_edge<<<nbE,256,0,stream>>>(h_ids, t_ids, dist, cbfs, E);
    k_bfs_comb<<<nbN,256,0,stream>>>(dist, cbfs, it<2, N);
  }

  // ---- small dense ----
  k_smalls<<<7,256,0,stream>>>(dist_e, W_enc, distW, nontext, encnt, q, W1, b1, bias2);

  // ---- relC = rel @ [WmB0 | WmB1 | W1r] ----
  k_bgemm<768,1><<<CDIV(R,32),256,0,stream>>>(rel, nullptr, BIGK1, pbRelC, relC,
      nullptr,nullptr,nullptr,nullptr,nullptr,nullptr,nullptr,nullptr,nullptr, R, 256);

  // ---- encoder (fused PE epilogue, dual fp32+bf16 h) ----
  k_bgemm<256,3><<<CDIV(Ntext,32),256,0,stream>>>(ent, nullptr, BIGK1, pbWenc, B1,
      hB1, nullptr, b_enc, W_enc, pe4, dist, topic, amask, distW, Ntext, 256);
  k_encnt_fill<<<N-Ntext,256,0,stream>>>(encnt, b_enc, W_enc, pe4, dist, topic, amask, distW, B1, hB1, Ntext);

  // ---- 2-layer gated GNN ----
  for (int l=0;l<2;l++){
    const u16* pT = l ? pbWmT1 : pbWmT0;
    const u16* pGU = l ? pbGU1 : pbGU0;
    float* hinF  = l ? B2 : B1;
    u16*   hinB  = l ? hB2 : hB1;
    float* houtF = l ? B1 : B2;
    u16*   houtB = l ? hB1 : hB2;
    // hm = h @ Wm_top  (bf16 A, bf16 out)
    k_bgemm<256,1><<<CDIV(N,32),256,0,stream>>>(nullptr, hinB, 0, pT, hmB,
        nullptr,nullptr,nullptr,nullptr,nullptr,nullptr,nullptr,nullptr,nullptr, N, 256);
    // agg = gather relu(hm[h]+mrel[r])
    k_agg<<<CDIV(N,4),256,0,stream>>>(offs, degiI, ehr, hmB, relC, l*256, aggB, N);
    // merged gate/upd GEMM + fused gated residual
    k_bgemm<512,4><<<CDIV(N,32),256,0,stream>>>(hinF, aggB, 256, pGU, houtF,
        houtB, hinF, nullptr,nullptr,nullptr,nullptr,nullptr,nullptr,nullptr, N, 512);
  }

  // ---- UHT = h @ (W_out @ [W1h|W1t])  (bf16 A = hB1, out into B2) ----
  k_bgemm<512,1><<<CDIV(N,32),256,0,stream>>>(nullptr, hB1, 0, pbWcomb, UHT,
      nullptr,nullptr,nullptr,nullptr,nullptr,nullptr,nullptr,nullptr,nullptr, N, 256);

  // ---- final scorer + anchor patch ----
  k_score<<<CDIV(E,4),256,0,stream>>>(h_ids, r_ids, t_ids, UHT, relC, bias2, topic,
                                      W1+(size_t)1024*256, W2, b2, out, E);
  k_patch<<<8,256,0,stream>>>(ai, as, h_ids, r_ids, t_ids, UHT, relC, bias2, topic,
                              W1+(size_t)1024*256, W2, b2, out);
}